// Round 1
// baseline (2057.646 us; speedup 1.0000x reference)
//
#include <hip/hip_runtime.h>
#include <hip/hip_bf16.h>
#include <math.h>

#define B_DIM 64
#define T_DIM 512
#define D_DIM 1024
#define TT (T_DIM * T_DIM)   // 262144 elems
#define TD (T_DIM * D_DIM)   // 524288 elems

// fp32 tiled GEMM config: 128x128 tile, BK=16, 256 threads, 8x8 per thread
#define BM 128
#define BN 128
#define BKK 16
#define APITCH 132  // +4 pad: keeps 16B alignment for float4 reads, reduces write conflicts

// ---------------------------------------------------------------------------
// LDS staging helpers
// ---------------------------------------------------------------------------

// Bs swizzled layout: elem(k, col) = k*128 + ((col&4)<<4) + ((col>>3)<<2) + (col&3)
// so that inner-loop reads (float4 at k*128 + tx*4 and k*128 + 64 + tx*4) are
// 16B-consecutive across the 16 tx lanes -> conflict-free.

// A row-major [M][K] source -> As[k][m] (transpose-scatter)
__device__ __forceinline__ void stage_a_rowmajor(float* As, const float* __restrict__ A,
                                                 int lda, int tid) {
#pragma unroll
    for (int i = 0; i < 2; ++i) {
        int idx = tid + i * 256;
        int r = idx >> 2;
        int k4 = (idx & 3) << 2;
        float4 v = *reinterpret_cast<const float4*>(&A[(size_t)r * lda + k4]);
        As[(k4 + 0) * APITCH + r] = v.x;
        As[(k4 + 1) * APITCH + r] = v.y;
        As[(k4 + 2) * APITCH + r] = v.z;
        As[(k4 + 3) * APITCH + r] = v.w;
    }
}

// Same but applies w = exp(x - rowmax[r])  (for q2_align: A = att rows)
__device__ __forceinline__ void stage_a_rowmajor_exp(float* As, const float* __restrict__ A,
                                                     int lda, const float* __restrict__ rowmax,
                                                     int tid) {
#pragma unroll
    for (int i = 0; i < 2; ++i) {
        int idx = tid + i * 256;
        int r = idx >> 2;
        int k4 = (idx & 3) << 2;
        float4 v = *reinterpret_cast<const float4*>(&A[(size_t)r * lda + k4]);
        float m = rowmax[r];
        As[(k4 + 0) * APITCH + r] = __expf(v.x - m);
        As[(k4 + 1) * APITCH + r] = __expf(v.y - m);
        As[(k4 + 2) * APITCH + r] = __expf(v.z - m);
        As[(k4 + 3) * APITCH + r] = __expf(v.w - m);
    }
}

// A col-major source (S[k][m], row pitch lds) -> As[k][m], applies exp(x - colmax[m])
// (for q1_align: A = att^T, so source rows are att t-rows)
__device__ __forceinline__ void stage_a_colmajor_exp(float* As, const float* __restrict__ S,
                                                     int lds, const float* __restrict__ colmax,
                                                     int tid) {
#pragma unroll
    for (int i = 0; i < 2; ++i) {
        int idx = tid + i * 256;
        int k = idx >> 5;
        int m4 = (idx & 31) << 2;
        float4 v = *reinterpret_cast<const float4*>(&S[(size_t)k * lds + m4]);
        float4 c = *reinterpret_cast<const float4*>(&colmax[m4]);
        float4 o;
        o.x = __expf(v.x - c.x);
        o.y = __expf(v.y - c.y);
        o.z = __expf(v.z - c.z);
        o.w = __expf(v.w - c.w);
        *reinterpret_cast<float4*>(&As[k * APITCH + m4]) = o;
    }
}

// B row-major [K][N] source -> swizzled Bs
__device__ __forceinline__ void stage_b_rowmajor(float* Bs, const float* __restrict__ Bp,
                                                 int ldb, int tid) {
#pragma unroll
    for (int i = 0; i < 2; ++i) {
        int idx = tid + i * 256;
        int k = idx >> 5;
        int c4 = idx & 31;
        float4 v = *reinterpret_cast<const float4*>(&Bp[(size_t)k * ldb + (c4 << 2)]);
        *reinterpret_cast<float4*>(&Bs[k * BN + ((c4 & 1) << 6) + ((c4 >> 1) << 2)]) = v;
    }
}

// B = Q^T where Q is [N][K] row-major (att GEMM: B[k=e][s] = q2[s][e])
__device__ __forceinline__ void stage_b_transpose(float* Bs, const float* __restrict__ Q,
                                                  int ldq, int tid) {
#pragma unroll
    for (int i = 0; i < 2; ++i) {
        int idx = tid + i * 256;
        int s = idx >> 2;
        int e4 = (idx & 3) << 2;
        float4 v = *reinterpret_cast<const float4*>(&Q[(size_t)s * ldq + e4]);
        int sw = ((s & 4) << 4) + ((s >> 3) << 2) + (s & 3);
        Bs[(e4 + 0) * BN + sw] = v.x;
        Bs[(e4 + 1) * BN + sw] = v.y;
        Bs[(e4 + 2) * BN + sw] = v.z;
        Bs[(e4 + 3) * BN + sw] = v.w;
    }
}

__device__ __forceinline__ void gemm_inner(const float* As, const float* Bs,
                                           float acc[8][8], int tx, int ty) {
#pragma unroll
    for (int k = 0; k < BKK; ++k) {
        float4 a0 = *reinterpret_cast<const float4*>(&As[k * APITCH + ty * 8]);
        float4 a1 = *reinterpret_cast<const float4*>(&As[k * APITCH + ty * 8 + 4]);
        float4 b0 = *reinterpret_cast<const float4*>(&Bs[k * BN + tx * 4]);
        float4 b1 = *reinterpret_cast<const float4*>(&Bs[k * BN + 64 + tx * 4]);
        float a[8] = {a0.x, a0.y, a0.z, a0.w, a1.x, a1.y, a1.z, a1.w};
        float b[8] = {b0.x, b0.y, b0.z, b0.w, b1.x, b1.y, b1.z, b1.w};
#pragma unroll
        for (int i = 0; i < 8; ++i)
#pragma unroll
            for (int j = 0; j < 8; ++j)
                acc[i][j] = fmaf(a[i], b[j], acc[i][j]);
    }
}

// ---------------------------------------------------------------------------
// K1: qU = q1 @ U        M = C*512 (chunk rows), N = K = 1024
// ---------------------------------------------------------------------------
__global__ __launch_bounds__(256) void k_gemm_qU(const float* __restrict__ q1,
                                                 const float* __restrict__ U,
                                                 float* __restrict__ qU, int b0) {
    __shared__ float As[BKK * APITCH];
    __shared__ float Bs[BKK * BN];
    int tid = threadIdx.x, tx = tid & 15, ty = tid >> 4;
    int m0 = blockIdx.y * BM;
    int n0 = blockIdx.x * BN;
    const float* Abase = q1 + (size_t)b0 * TD + (size_t)m0 * D_DIM;
    const float* Bbase = U + n0;
    float acc[8][8] = {};
    for (int kt = 0; kt < D_DIM; kt += BKK) {
        stage_a_rowmajor(As, Abase + kt, D_DIM, tid);
        stage_b_rowmajor(Bs, Bbase + (size_t)kt * D_DIM, D_DIM, tid);
        __syncthreads();
        gemm_inner(As, Bs, acc, tx, ty);
        __syncthreads();
    }
    float* Cp = qU + (size_t)m0 * D_DIM + n0;
#pragma unroll
    for (int i = 0; i < 8; ++i) {
        int r = ty * 8 + i;
        float4 o0 = {acc[i][0], acc[i][1], acc[i][2], acc[i][3]};
        float4 o1 = {acc[i][4], acc[i][5], acc[i][6], acc[i][7]};
        *reinterpret_cast<float4*>(&Cp[(size_t)r * D_DIM + tx * 8]) = o0;
        *reinterpret_cast<float4*>(&Cp[(size_t)r * D_DIM + tx * 8 + 4]) = o1;
    }
}

// ---------------------------------------------------------------------------
// K2: att = relu(qU @ q2^T)   per batch: M=N=512 (t,s), K=1024 (e)
// ---------------------------------------------------------------------------
__global__ __launch_bounds__(256) void k_att(const float* __restrict__ qU,
                                             const float* __restrict__ q2,
                                             float* __restrict__ att, int b0) {
    __shared__ float As[BKK * APITCH];
    __shared__ float Bs[BKK * BN];
    int tid = threadIdx.x, tx = tid & 15, ty = tid >> 4;
    int lb = blockIdx.z;
    int m0 = blockIdx.y * BM;
    int n0 = blockIdx.x * BN;
    const float* Abase = qU + (size_t)lb * TD + (size_t)m0 * D_DIM;
    const float* Qbase = q2 + (size_t)(b0 + lb) * TD + (size_t)n0 * D_DIM;
    float acc[8][8] = {};
    for (int kt = 0; kt < D_DIM; kt += BKK) {
        stage_a_rowmajor(As, Abase + kt, D_DIM, tid);
        stage_b_transpose(Bs, Qbase + kt, D_DIM, tid);
        __syncthreads();
        gemm_inner(As, Bs, acc, tx, ty);
        __syncthreads();
    }
    float* Cp = att + (size_t)lb * TT + (size_t)m0 * T_DIM + n0;
#pragma unroll
    for (int i = 0; i < 8; ++i) {
        int r = ty * 8 + i;
        float4 o0 = {fmaxf(acc[i][0], 0.f), fmaxf(acc[i][1], 0.f), fmaxf(acc[i][2], 0.f), fmaxf(acc[i][3], 0.f)};
        float4 o1 = {fmaxf(acc[i][4], 0.f), fmaxf(acc[i][5], 0.f), fmaxf(acc[i][6], 0.f), fmaxf(acc[i][7], 0.f)};
        *reinterpret_cast<float4*>(&Cp[(size_t)r * T_DIM + tx * 8]) = o0;
        *reinterpret_cast<float4*>(&Cp[(size_t)r * T_DIM + tx * 8 + 4]) = o1;
    }
}

// ---------------------------------------------------------------------------
// K3a: row stats (softmax over axis=2): per (b,t): max_s, sum_s exp
// one wave per row
// ---------------------------------------------------------------------------
__global__ __launch_bounds__(256) void k_rowstats(const float* __restrict__ att,
                                                  float* __restrict__ rmax,
                                                  float* __restrict__ rsum, int b0) {
    int wave = threadIdx.x >> 6, lane = threadIdx.x & 63;
    int lr = blockIdx.x * 4 + wave;  // chunk-local row index [0, C*512)
    const float4* row = reinterpret_cast<const float4*>(att + (size_t)lr * T_DIM);
    float4 v0 = row[lane];
    float4 v1 = row[lane + 64];
    float m = fmaxf(fmaxf(fmaxf(v0.x, v0.y), fmaxf(v0.z, v0.w)),
                    fmaxf(fmaxf(v1.x, v1.y), fmaxf(v1.z, v1.w)));
#pragma unroll
    for (int off = 32; off >= 1; off >>= 1) m = fmaxf(m, __shfl_xor(m, off));
    float s = __expf(v0.x - m) + __expf(v0.y - m) + __expf(v0.z - m) + __expf(v0.w - m)
            + __expf(v1.x - m) + __expf(v1.y - m) + __expf(v1.z - m) + __expf(v1.w - m);
#pragma unroll
    for (int off = 32; off >= 1; off >>= 1) s += __shfl_xor(s, off);
    if (lane == 0) {
        size_t gr = (size_t)b0 * T_DIM + lr;
        rmax[gr] = m;
        rsum[gr] = s;
    }
}

// ---------------------------------------------------------------------------
// K3b: col stats (softmax over axis=1): per (b,s): max_t, sum_t exp (online)
// ---------------------------------------------------------------------------
__global__ __launch_bounds__(256) void k_colstats(const float* __restrict__ att,
                                                  float* __restrict__ cmax,
                                                  float* __restrict__ csum, int b0) {
    int lb = blockIdx.y;
    int s = blockIdx.x * 256 + threadIdx.x;
    const float* base = att + (size_t)lb * TT + s;
    float m = -INFINITY, sum = 0.f;
    for (int t = 0; t < T_DIM; ++t) {
        float x = base[(size_t)t * T_DIM];
        float nm = fmaxf(m, x);
        sum = sum * __expf(m - nm) + __expf(x - nm);
        m = nm;
    }
    size_t g = (size_t)(b0 + lb) * T_DIM + s;
    cmax[g] = m;
    csum[g] = sum;
}

// ---------------------------------------------------------------------------
// K4: q2_align[b,t,d] = (1/rsum[t]) * sum_s exp(att[t,s]-rmax[t]) * q2[b,s,d]
//     per batch: M=512 (t), N=1024 (d), K=512 (s)
// ---------------------------------------------------------------------------
__global__ __launch_bounds__(256) void k_q2align(const float* __restrict__ att,
                                                 const float* __restrict__ q2,
                                                 const float* __restrict__ rmax,
                                                 const float* __restrict__ rsum,
                                                 float* __restrict__ out, int b0) {
    __shared__ float As[BKK * APITCH];
    __shared__ float Bs[BKK * BN];
    int tid = threadIdx.x, tx = tid & 15, ty = tid >> 4;
    int lb = blockIdx.z;
    int m0 = blockIdx.y * BM;
    int n0 = blockIdx.x * BN;
    const float* Abase = att + (size_t)lb * TT + (size_t)m0 * T_DIM;
    const float* rmaxp = rmax + (size_t)(b0 + lb) * T_DIM + m0;
    const float* rsump = rsum + (size_t)(b0 + lb) * T_DIM + m0;
    const float* Bbase = q2 + (size_t)(b0 + lb) * TD + n0;
    float acc[8][8] = {};
    for (int kt = 0; kt < T_DIM; kt += BKK) {
        stage_a_rowmajor_exp(As, Abase + kt, T_DIM, rmaxp, tid);
        stage_b_rowmajor(Bs, Bbase + (size_t)kt * D_DIM, D_DIM, tid);
        __syncthreads();
        gemm_inner(As, Bs, acc, tx, ty);
        __syncthreads();
    }
    // q2_align is second output: offset B*T*D
    float* Cp = out + (size_t)B_DIM * TD + (size_t)(b0 + lb) * TD + (size_t)m0 * D_DIM + n0;
#pragma unroll
    for (int i = 0; i < 8; ++i) {
        int r = ty * 8 + i;
        float inv = 1.0f / rsump[r];
        float4 o0 = {acc[i][0] * inv, acc[i][1] * inv, acc[i][2] * inv, acc[i][3] * inv};
        float4 o1 = {acc[i][4] * inv, acc[i][5] * inv, acc[i][6] * inv, acc[i][7] * inv};
        *reinterpret_cast<float4*>(&Cp[(size_t)r * D_DIM + tx * 8]) = o0;
        *reinterpret_cast<float4*>(&Cp[(size_t)r * D_DIM + tx * 8 + 4]) = o1;
    }
}

// ---------------------------------------------------------------------------
// K5: q1_align[b,s,d] = (1/csum[s]) * sum_t exp(att[t,s]-cmax[s]) * q1[b,t,d]
//     per batch: M=512 (s), N=1024 (d), K=512 (t); A = att^T (col-major source)
// ---------------------------------------------------------------------------
__global__ __launch_bounds__(256) void k_q1align(const float* __restrict__ att,
                                                 const float* __restrict__ q1,
                                                 const float* __restrict__ cmax,
                                                 const float* __restrict__ csum,
                                                 float* __restrict__ out, int b0) {
    __shared__ float As[BKK * APITCH];
    __shared__ float Bs[BKK * BN];
    int tid = threadIdx.x, tx = tid & 15, ty = tid >> 4;
    int lb = blockIdx.z;
    int m0 = blockIdx.y * BM;  // s-tile
    int n0 = blockIdx.x * BN;  // d-tile
    const float* Sbase = att + (size_t)lb * TT + m0;         // S[k=t][m=s]
    const float* cmaxp = cmax + (size_t)(b0 + lb) * T_DIM + m0;
    const float* csump = csum + (size_t)(b0 + lb) * T_DIM + m0;
    const float* Bbase = q1 + (size_t)(b0 + lb) * TD + n0;
    float acc[8][8] = {};
    for (int kt = 0; kt < T_DIM; kt += BKK) {
        stage_a_colmajor_exp(As, Sbase + (size_t)kt * T_DIM, T_DIM, cmaxp, tid);
        stage_b_rowmajor(Bs, Bbase + (size_t)kt * D_DIM, D_DIM, tid);
        __syncthreads();
        gemm_inner(As, Bs, acc, tx, ty);
        __syncthreads();
    }
    // q1_align is first output
    float* Cp = out + (size_t)(b0 + lb) * TD + (size_t)m0 * D_DIM + n0;
#pragma unroll
    for (int i = 0; i < 8; ++i) {
        int r = ty * 8 + i;
        float inv = 1.0f / csump[r];
        float4 o0 = {acc[i][0] * inv, acc[i][1] * inv, acc[i][2] * inv, acc[i][3] * inv};
        float4 o1 = {acc[i][4] * inv, acc[i][5] * inv, acc[i][6] * inv, acc[i][7] * inv};
        *reinterpret_cast<float4*>(&Cp[(size_t)r * D_DIM + tx * 8]) = o0;
        *reinterpret_cast<float4*>(&Cp[(size_t)r * D_DIM + tx * 8 + 4]) = o1;
    }
}

// ---------------------------------------------------------------------------
extern "C" void kernel_launch(void* const* d_in, const int* in_sizes, int n_in,
                              void* d_out, int out_size, void* d_ws, size_t ws_size,
                              hipStream_t stream) {
    const float* q1 = (const float*)d_in[0];
    const float* q2 = (const float*)d_in[1];
    const float* U  = (const float*)d_in[2];
    float* out = (float*)d_out;

    // ws layout: [rmax | rsum | cmax | csum] (each B*T f32) then qU (C*T*D) then att (C*T*T)
    const size_t statsElems = 4ull * B_DIM * T_DIM;
    float* rmax = (float*)d_ws;
    float* rsum = rmax + (size_t)B_DIM * T_DIM;
    float* cmax = rsum + (size_t)B_DIM * T_DIM;
    float* csum = cmax + (size_t)B_DIM * T_DIM;
    float* scratch = csum + (size_t)B_DIM * T_DIM;

    size_t availFloats = (ws_size > statsElems * 4) ? (ws_size - statsElems * 4) / 4 : 0;
    int C = 64;
    while (C > 1 && (size_t)C * (TD + TT) > availFloats) C >>= 1;
    if ((size_t)C * (TD + TT) > availFloats) return;  // ws too small: fail loudly

    float* qU  = scratch;
    float* att = qU + (size_t)C * TD;

    for (int b0 = 0; b0 < B_DIM; b0 += C) {
        k_gemm_qU<<<dim3(D_DIM / BN, C * (T_DIM / BM)), 256, 0, stream>>>(q1, U, qU, b0);
        k_att<<<dim3(T_DIM / BN, T_DIM / BM, C), 256, 0, stream>>>(qU, q2, att, b0);
        k_rowstats<<<dim3(C * T_DIM / 4), 256, 0, stream>>>(att, rmax, rsum, b0);
        k_colstats<<<dim3(T_DIM / 256, C), 256, 0, stream>>>(att, cmax, csum, b0);
        k_q2align<<<dim3(D_DIM / BN, T_DIM / BM, C), 256, 0, stream>>>(att, q2, rmax, rsum, out, b0);
        k_q1align<<<dim3(D_DIM / BN, T_DIM / BM, C), 256, 0, stream>>>(att, q1, cmax, csum, out, b0);
    }
}

// Round 2
// 526.179 us; speedup vs baseline: 3.9105x; 3.9105x over previous
//
#include <hip/hip_runtime.h>
#include <hip/hip_bf16.h>
#include <math.h>

#define B_DIM 64
#define T_DIM 512
#define D_DIM 1024
#define TT (T_DIM * T_DIM)   // 262144
#define TD (T_DIM * D_DIM)   // 524288

typedef _Float16 f16;
typedef f16 f16x4 __attribute__((ext_vector_type(4)));
typedef f16 f16x8 __attribute__((ext_vector_type(8)));
typedef float f32x4 __attribute__((ext_vector_type(4)));

// ===========================================================================
// FP16 MFMA path
// ===========================================================================

__device__ __forceinline__ void gld_lds16(const void* g, void* l) {
    __builtin_amdgcn_global_load_lds(
        (const __attribute__((address_space(1))) void*)g,
        (__attribute__((address_space(3))) void*)l, 16, 0, 0);
}

// Generic MFMA GEMM: C[M][N] = A[M][K] @ Bt[N][K]^T, 128x128 tile, BK=32.
// 256 threads = 4 waves, each wave 64x64 = 4x4 frags of 16x16x32.
// LDS tiles [128 rows][4 slots of 8 f16], slot-swizzled: LDS[r][j] holds
// global k-chunk j ^ ((r>>1)&3)  (applied on BOTH source addr and frag read).
// EPI: 0 = f16 out, no scale (qU)     1 = f32 out + relu (att)
//      2,3 = f32 out * (1/scale[row]) (aligns)
template <int EPI>
__global__ __launch_bounds__(256) void k_mfma(
        const f16* __restrict__ A, int lda,
        const f16* __restrict__ Bt, int ldb, int K,
        void* __restrict__ Cout, int ldc,
        const float* __restrict__ scale,
        long batchA, long batchB, long batchC, long batchS) {
    __shared__ f16 Ah[128 * 32];
    __shared__ f16 Bh[128 * 32];
    const int tid = threadIdx.x;
    const int lane = tid & 63, w = tid >> 6;
    const int z = blockIdx.z;
    const f16* Ab = A + (long)z * batchA + (long)(blockIdx.y * 128) * lda;
    const f16* Bb = Bt + (long)z * batchB + (long)(blockIdx.x * 128) * ldb;

    const int wm = (w & 1) * 64, wn = (w >> 1) * 64;
    f32x4 acc[4][4] = {};

    // staging decode (chunk c -> row m, LDS slot j, global slot s)
    const int c0 = w * 64 + lane;
    const int m0s = c0 >> 2, j0 = c0 & 3;
    const int c1 = 256 + c0;
    const int m1s = c1 >> 2, j1 = c1 & 3;
    const int s0 = j0 ^ ((m0s >> 1) & 3);
    const int s1 = j1 ^ ((m1s >> 1) & 3);
    f16* lA0 = Ah + (w * 64) * 8;          // wave-uniform LDS bases
    f16* lA1 = Ah + (256 + w * 64) * 8;
    f16* lB0 = Bh + (w * 64) * 8;
    f16* lB1 = Bh + (256 + w * 64) * 8;

    const int g = lane >> 4;
    const int rA = wm + (lane & 15);
    const int rB = wn + (lane & 15);

    for (int kt = 0; kt < K; kt += 32) {
        gld_lds16(Ab + (long)m0s * lda + kt + s0 * 8, lA0);
        gld_lds16(Ab + (long)m1s * lda + kt + s1 * 8, lA1);
        gld_lds16(Bb + (long)m0s * ldb + kt + s0 * 8, lB0);
        gld_lds16(Bb + (long)m1s * ldb + kt + s1 * 8, lB1);
        __syncthreads();
        f16x8 af[4], bf[4];
#pragma unroll
        for (int f = 0; f < 4; ++f) {
            int ra = rA + f * 16;
            int sa = g ^ ((ra >> 1) & 3);
            af[f] = *(const f16x8*)(Ah + ra * 32 + sa * 8);
            int rb = rB + f * 16;
            int sb = g ^ ((rb >> 1) & 3);
            bf[f] = *(const f16x8*)(Bh + rb * 32 + sb * 8);
        }
#pragma unroll
        for (int i = 0; i < 4; ++i)
#pragma unroll
            for (int j = 0; j < 4; ++j)
                acc[i][j] = __builtin_amdgcn_mfma_f32_16x16x32_f16(af[i], bf[j], acc[i][j], 0, 0, 0);
        __syncthreads();
    }

    const int row0 = blockIdx.y * 128 + wm + (lane >> 4) * 4;
    const int col0 = blockIdx.x * 128 + wn + (lane & 15);
    if constexpr (EPI == 0) {
        f16* C = (f16*)Cout;
#pragma unroll
        for (int f = 0; f < 4; ++f)
#pragma unroll
            for (int r = 0; r < 4; ++r) {
                long row = row0 + f * 16 + r;
#pragma unroll
                for (int fn = 0; fn < 4; ++fn)
                    C[row * ldc + col0 + fn * 16] = (f16)acc[f][fn][r];
            }
    } else if constexpr (EPI == 1) {
        float* C = (float*)Cout + (long)z * batchC;
#pragma unroll
        for (int f = 0; f < 4; ++f)
#pragma unroll
            for (int r = 0; r < 4; ++r) {
                long row = row0 + f * 16 + r;
#pragma unroll
                for (int fn = 0; fn < 4; ++fn)
                    C[row * ldc + col0 + fn * 16] = fmaxf(acc[f][fn][r], 0.0f);
            }
    } else {
        float* C = (float*)Cout + (long)z * batchC;
        const float* sz = scale + (long)z * batchS;
#pragma unroll
        for (int f = 0; f < 4; ++f)
#pragma unroll
            for (int r = 0; r < 4; ++r) {
                long row = row0 + f * 16 + r;
                float inv = 1.0f / sz[row];
#pragma unroll
                for (int fn = 0; fn < 4; ++fn)
                    C[row * ldc + col0 + fn * 16] = acc[f][fn][r] * inv;
            }
    }
}

// cast q [B][T][D] f32 -> qh fp16 [B][T][D] and qht fp16 [B][D][T]
__global__ __launch_bounds__(256) void k_cast_both(const float* __restrict__ src,
                                                   f16* __restrict__ dst,
                                                   f16* __restrict__ dstT) {
    __shared__ f16 tr[64][72];
    int b = blockIdx.z;
    int d0 = blockIdx.x * 64, t0 = blockIdx.y * 64;
    const float* S = src + ((size_t)b * T_DIM + t0) * D_DIM + d0;
    f16* Dr = dst + ((size_t)b * T_DIM + t0) * D_DIM + d0;
    int tid = threadIdx.x;
    int rr = tid >> 4, cc = (tid & 15) * 4;
#pragma unroll
    for (int i = 0; i < 4; ++i) {
        int r = rr + i * 16;
        float4 v = *(const float4*)(S + (size_t)r * D_DIM + cc);
        f16x4 h = {(f16)v.x, (f16)v.y, (f16)v.z, (f16)v.w};
        *(f16x4*)(Dr + (size_t)r * D_DIM + cc) = h;
        tr[cc + 0][r] = h[0];
        tr[cc + 1][r] = h[1];
        tr[cc + 2][r] = h[2];
        tr[cc + 3][r] = h[3];
    }
    __syncthreads();
    f16* Dt = dstT + ((size_t)b * D_DIM + d0) * T_DIM + t0;
    int r2 = tid >> 3, c8 = (tid & 7) * 8;
#pragma unroll
    for (int i = 0; i < 2; ++i) {
        int d = r2 + i * 32;
        f16x8 vv = *(const f16x8*)(&tr[d][c8]);
        *(f16x8*)(Dt + (size_t)d * T_DIM + c8) = vv;
    }
}

// U [K=1024][N=1024] f32 -> Uht fp16 [N][K]
__global__ __launch_bounds__(256) void k_castU(const float* __restrict__ U,
                                               f16* __restrict__ Uht) {
    __shared__ f16 tr[64][72];
    int n0 = blockIdx.x * 64, k0 = blockIdx.y * 64;
    int tid = threadIdx.x;
    int rr = tid >> 4, cc = (tid & 15) * 4;
#pragma unroll
    for (int i = 0; i < 4; ++i) {
        int r = rr + i * 16;
        float4 v = *(const float4*)(U + (size_t)(k0 + r) * D_DIM + n0 + cc);
        tr[cc + 0][r] = (f16)v.x;
        tr[cc + 1][r] = (f16)v.y;
        tr[cc + 2][r] = (f16)v.z;
        tr[cc + 3][r] = (f16)v.w;
    }
    __syncthreads();
    int r2 = tid >> 3, c8 = (tid & 7) * 8;
#pragma unroll
    for (int i = 0; i < 2; ++i) {
        int n = r2 + i * 32;
        f16x8 vv = *(const f16x8*)(&tr[n][c8]);
        *(f16x8*)(Uht + (size_t)(n0 + n) * D_DIM + k0 + c8) = vv;
    }
}

// att f32 (chunk-local) -> P2h[t][s] = exp(att - rmax[t]), P1h[s][t] = exp(att - cmax[s])
__global__ __launch_bounds__(256) void k_pconv(const float* __restrict__ att,
                                               const float* __restrict__ rmax,
                                               const float* __restrict__ cmax,
                                               f16* __restrict__ P2, f16* __restrict__ P1,
                                               int b0) {
    __shared__ f16 tr[64][72];
    int z = blockIdx.z;
    int t0 = blockIdx.y * 64, s0 = blockIdx.x * 64;
    const float* S = att + (size_t)z * TT + (size_t)t0 * T_DIM + s0;
    const float* rm = rmax + (size_t)(b0 + z) * T_DIM + t0;
    const float* cm = cmax + (size_t)(b0 + z) * T_DIM + s0;
    int tid = threadIdx.x;
    int rr = tid >> 4, cc = (tid & 15) * 4;
#pragma unroll
    for (int i = 0; i < 4; ++i) {
        int r = rr + i * 16;
        float4 v = *(const float4*)(S + (size_t)r * T_DIM + cc);
        float m = rm[r];
        f16x4 p2 = {(f16)__expf(v.x - m), (f16)__expf(v.y - m),
                    (f16)__expf(v.z - m), (f16)__expf(v.w - m)};
        *(f16x4*)(P2 + (size_t)z * TT + (size_t)(t0 + r) * T_DIM + s0 + cc) = p2;
        float4 c4 = *(const float4*)(cm + cc);
        tr[cc + 0][r] = (f16)__expf(v.x - c4.x);
        tr[cc + 1][r] = (f16)__expf(v.y - c4.y);
        tr[cc + 2][r] = (f16)__expf(v.z - c4.z);
        tr[cc + 3][r] = (f16)__expf(v.w - c4.w);
    }
    __syncthreads();
    int r2 = tid >> 3, c8 = (tid & 7) * 8;
#pragma unroll
    for (int i = 0; i < 2; ++i) {
        int s = r2 + i * 32;
        f16x8 vv = *(const f16x8*)(&tr[s][c8]);
        *(f16x8*)(P1 + (size_t)z * TT + (size_t)(s0 + s) * T_DIM + t0 + c8) = vv;
    }
}

// ---------------------------------------------------------------------------
// stats (shared by both paths); att is chunk-local f32
// ---------------------------------------------------------------------------
__global__ __launch_bounds__(256) void k_rowstats(const float* __restrict__ att,
                                                  float* __restrict__ rmax,
                                                  float* __restrict__ rsum, int b0) {
    int wave = threadIdx.x >> 6, lane = threadIdx.x & 63;
    int lr = blockIdx.x * 4 + wave;
    const float4* row = reinterpret_cast<const float4*>(att + (size_t)lr * T_DIM);
    float4 v0 = row[lane];
    float4 v1 = row[lane + 64];
    float m = fmaxf(fmaxf(fmaxf(v0.x, v0.y), fmaxf(v0.z, v0.w)),
                    fmaxf(fmaxf(v1.x, v1.y), fmaxf(v1.z, v1.w)));
#pragma unroll
    for (int off = 32; off >= 1; off >>= 1) m = fmaxf(m, __shfl_xor(m, off));
    float s = __expf(v0.x - m) + __expf(v0.y - m) + __expf(v0.z - m) + __expf(v0.w - m)
            + __expf(v1.x - m) + __expf(v1.y - m) + __expf(v1.z - m) + __expf(v1.w - m);
#pragma unroll
    for (int off = 32; off >= 1; off >>= 1) s += __shfl_xor(s, off);
    if (lane == 0) {
        size_t gr = (size_t)b0 * T_DIM + lr;
        rmax[gr] = m;
        rsum[gr] = s;
    }
}

__global__ __launch_bounds__(256) void k_colstats(const float* __restrict__ att,
                                                  float* __restrict__ cmax,
                                                  float* __restrict__ csum, int b0) {
    int lb = blockIdx.y;
    int s = blockIdx.x * 256 + threadIdx.x;
    const float* base = att + (size_t)lb * TT + s;
    float m = -INFINITY, sum = 0.f;
    for (int t = 0; t < T_DIM; ++t) {
        float x = base[(size_t)t * T_DIM];
        float nm = fmaxf(m, x);
        sum = sum * __expf(m - nm) + __expf(x - nm);
        m = nm;
    }
    size_t g = (size_t)(b0 + lb) * T_DIM + s;
    cmax[g] = m;
    csum[g] = sum;
}

// ===========================================================================
// FP32 fallback path (round-1 proven kernels) — used only if ws too small
// ===========================================================================
#define BM 128
#define BN 128
#define BKK 16
#define APITCH 132

__device__ __forceinline__ void stage_a_rowmajor(float* As, const float* __restrict__ A,
                                                 int lda, int tid) {
#pragma unroll
    for (int i = 0; i < 2; ++i) {
        int idx = tid + i * 256;
        int r = idx >> 2;
        int k4 = (idx & 3) << 2;
        float4 v = *reinterpret_cast<const float4*>(&A[(size_t)r * lda + k4]);
        As[(k4 + 0) * APITCH + r] = v.x;
        As[(k4 + 1) * APITCH + r] = v.y;
        As[(k4 + 2) * APITCH + r] = v.z;
        As[(k4 + 3) * APITCH + r] = v.w;
    }
}
__device__ __forceinline__ void stage_a_rowmajor_exp(float* As, const float* __restrict__ A,
                                                     int lda, const float* __restrict__ rowmax,
                                                     int tid) {
#pragma unroll
    for (int i = 0; i < 2; ++i) {
        int idx = tid + i * 256;
        int r = idx >> 2;
        int k4 = (idx & 3) << 2;
        float4 v = *reinterpret_cast<const float4*>(&A[(size_t)r * lda + k4]);
        float m = rowmax[r];
        As[(k4 + 0) * APITCH + r] = __expf(v.x - m);
        As[(k4 + 1) * APITCH + r] = __expf(v.y - m);
        As[(k4 + 2) * APITCH + r] = __expf(v.z - m);
        As[(k4 + 3) * APITCH + r] = __expf(v.w - m);
    }
}
__device__ __forceinline__ void stage_a_colmajor_exp(float* As, const float* __restrict__ S,
                                                     int lds, const float* __restrict__ colmax,
                                                     int tid) {
#pragma unroll
    for (int i = 0; i < 2; ++i) {
        int idx = tid + i * 256;
        int k = idx >> 5;
        int m4 = (idx & 31) << 2;
        float4 v = *reinterpret_cast<const float4*>(&S[(size_t)k * lds + m4]);
        float4 c = *reinterpret_cast<const float4*>(&colmax[m4]);
        float4 o;
        o.x = __expf(v.x - c.x); o.y = __expf(v.y - c.y);
        o.z = __expf(v.z - c.z); o.w = __expf(v.w - c.w);
        *reinterpret_cast<float4*>(&As[k * APITCH + m4]) = o;
    }
}
__device__ __forceinline__ void stage_b_rowmajor(float* Bs, const float* __restrict__ Bp,
                                                 int ldb, int tid) {
#pragma unroll
    for (int i = 0; i < 2; ++i) {
        int idx = tid + i * 256;
        int k = idx >> 5;
        int c4 = idx & 31;
        float4 v = *reinterpret_cast<const float4*>(&Bp[(size_t)k * ldb + (c4 << 2)]);
        *reinterpret_cast<float4*>(&Bs[k * BN + ((c4 & 1) << 6) + ((c4 >> 1) << 2)]) = v;
    }
}
__device__ __forceinline__ void stage_b_transpose(float* Bs, const float* __restrict__ Q,
                                                  int ldq, int tid) {
#pragma unroll
    for (int i = 0; i < 2; ++i) {
        int idx = tid + i * 256;
        int s = idx >> 2;
        int e4 = (idx & 3) << 2;
        float4 v = *reinterpret_cast<const float4*>(&Q[(size_t)s * ldq + e4]);
        int sw = ((s & 4) << 4) + ((s >> 3) << 2) + (s & 3);
        Bs[(e4 + 0) * BN + sw] = v.x;
        Bs[(e4 + 1) * BN + sw] = v.y;
        Bs[(e4 + 2) * BN + sw] = v.z;
        Bs[(e4 + 3) * BN + sw] = v.w;
    }
}
__device__ __forceinline__ void gemm_inner(const float* As, const float* Bs,
                                           float acc[8][8], int tx, int ty) {
#pragma unroll
    for (int k = 0; k < BKK; ++k) {
        float4 a0 = *reinterpret_cast<const float4*>(&As[k * APITCH + ty * 8]);
        float4 a1 = *reinterpret_cast<const float4*>(&As[k * APITCH + ty * 8 + 4]);
        float4 b0 = *reinterpret_cast<const float4*>(&Bs[k * BN + tx * 4]);
        float4 b1 = *reinterpret_cast<const float4*>(&Bs[k * BN + 64 + tx * 4]);
        float a[8] = {a0.x, a0.y, a0.z, a0.w, a1.x, a1.y, a1.z, a1.w};
        float b[8] = {b0.x, b0.y, b0.z, b0.w, b1.x, b1.y, b1.z, b1.w};
#pragma unroll
        for (int i = 0; i < 8; ++i)
#pragma unroll
            for (int j = 0; j < 8; ++j)
                acc[i][j] = fmaf(a[i], b[j], acc[i][j]);
    }
}
__global__ __launch_bounds__(256) void k_gemm_qU(const float* __restrict__ q1,
                                                 const float* __restrict__ U,
                                                 float* __restrict__ qU, int b0) {
    __shared__ float As[BKK * APITCH];
    __shared__ float Bs[BKK * BN];
    int tid = threadIdx.x, tx = tid & 15, ty = tid >> 4;
    int m0 = blockIdx.y * BM;
    int n0 = blockIdx.x * BN;
    const float* Abase = q1 + (size_t)b0 * TD + (size_t)m0 * D_DIM;
    const float* Bbase = U + n0;
    float acc[8][8] = {};
    for (int kt = 0; kt < D_DIM; kt += BKK) {
        stage_a_rowmajor(As, Abase + kt, D_DIM, tid);
        stage_b_rowmajor(Bs, Bbase + (size_t)kt * D_DIM, D_DIM, tid);
        __syncthreads();
        gemm_inner(As, Bs, acc, tx, ty);
        __syncthreads();
    }
    float* Cp = qU + (size_t)m0 * D_DIM + n0;
#pragma unroll
    for (int i = 0; i < 8; ++i) {
        int r = ty * 8 + i;
        float4 o0 = {acc[i][0], acc[i][1], acc[i][2], acc[i][3]};
        float4 o1 = {acc[i][4], acc[i][5], acc[i][6], acc[i][7]};
        *reinterpret_cast<float4*>(&Cp[(size_t)r * D_DIM + tx * 8]) = o0;
        *reinterpret_cast<float4*>(&Cp[(size_t)r * D_DIM + tx * 8 + 4]) = o1;
    }
}
__global__ __launch_bounds__(256) void k_att(const float* __restrict__ qU,
                                             const float* __restrict__ q2,
                                             float* __restrict__ att, int b0) {
    __shared__ float As[BKK * APITCH];
    __shared__ float Bs[BKK * BN];
    int tid = threadIdx.x, tx = tid & 15, ty = tid >> 4;
    int lb = blockIdx.z;
    int m0 = blockIdx.y * BM;
    int n0 = blockIdx.x * BN;
    const float* Abase = qU + (size_t)lb * TD + (size_t)m0 * D_DIM;
    const float* Qbase = q2 + (size_t)(b0 + lb) * TD + (size_t)n0 * D_DIM;
    float acc[8][8] = {};
    for (int kt = 0; kt < D_DIM; kt += BKK) {
        stage_a_rowmajor(As, Abase + kt, D_DIM, tid);
        stage_b_transpose(Bs, Qbase + kt, D_DIM, tid);
        __syncthreads();
        gemm_inner(As, Bs, acc, tx, ty);
        __syncthreads();
    }
    float* Cp = att + (size_t)lb * TT + (size_t)m0 * T_DIM + n0;
#pragma unroll
    for (int i = 0; i < 8; ++i) {
        int r = ty * 8 + i;
        float4 o0 = {fmaxf(acc[i][0], 0.f), fmaxf(acc[i][1], 0.f), fmaxf(acc[i][2], 0.f), fmaxf(acc[i][3], 0.f)};
        float4 o1 = {fmaxf(acc[i][4], 0.f), fmaxf(acc[i][5], 0.f), fmaxf(acc[i][6], 0.f), fmaxf(acc[i][7], 0.f)};
        *reinterpret_cast<float4*>(&Cp[(size_t)r * T_DIM + tx * 8]) = o0;
        *reinterpret_cast<float4*>(&Cp[(size_t)r * T_DIM + tx * 8 + 4]) = o1;
    }
}
__global__ __launch_bounds__(256) void k_q2align(const float* __restrict__ att,
                                                 const float* __restrict__ q2,
                                                 const float* __restrict__ rmax,
                                                 const float* __restrict__ rsum,
                                                 float* __restrict__ out, int b0) {
    __shared__ float As[BKK * APITCH];
    __shared__ float Bs[BKK * BN];
    int tid = threadIdx.x, tx = tid & 15, ty = tid >> 4;
    int lb = blockIdx.z;
    int m0 = blockIdx.y * BM;
    int n0 = blockIdx.x * BN;
    const float* Abase = att + (size_t)lb * TT + (size_t)m0 * T_DIM;
    const float* rmaxp = rmax + (size_t)(b0 + lb) * T_DIM + m0;
    const float* rsump = rsum + (size_t)(b0 + lb) * T_DIM + m0;
    const float* Bbase = q2 + (size_t)(b0 + lb) * TD + n0;
    float acc[8][8] = {};
    for (int kt = 0; kt < T_DIM; kt += BKK) {
        stage_a_rowmajor_exp(As, Abase + kt, T_DIM, rmaxp, tid);
        stage_b_rowmajor(Bs, Bbase + (size_t)kt * D_DIM, D_DIM, tid);
        __syncthreads();
        gemm_inner(As, Bs, acc, tx, ty);
        __syncthreads();
    }
    float* Cp = out + (size_t)B_DIM * TD + (size_t)(b0 + lb) * TD + (size_t)m0 * D_DIM + n0;
#pragma unroll
    for (int i = 0; i < 8; ++i) {
        int r = ty * 8 + i;
        float inv = 1.0f / rsump[r];
        float4 o0 = {acc[i][0] * inv, acc[i][1] * inv, acc[i][2] * inv, acc[i][3] * inv};
        float4 o1 = {acc[i][4] * inv, acc[i][5] * inv, acc[i][6] * inv, acc[i][7] * inv};
        *reinterpret_cast<float4*>(&Cp[(size_t)r * D_DIM + tx * 8]) = o0;
        *reinterpret_cast<float4*>(&Cp[(size_t)r * D_DIM + tx * 8 + 4]) = o1;
    }
}
__global__ __launch_bounds__(256) void k_q1align(const float* __restrict__ att,
                                                 const float* __restrict__ q1,
                                                 const float* __restrict__ cmax,
                                                 const float* __restrict__ csum,
                                                 float* __restrict__ out, int b0) {
    __shared__ float As[BKK * APITCH];
    __shared__ float Bs[BKK * BN];
    int tid = threadIdx.x, tx = tid & 15, ty = tid >> 4;
    int lb = blockIdx.z;
    int m0 = blockIdx.y * BM;
    int n0 = blockIdx.x * BN;
    const float* Sbase = att + (size_t)lb * TT + m0;
    const float* cmaxp = cmax + (size_t)(b0 + lb) * T_DIM + m0;
    const float* csump = csum + (size_t)(b0 + lb) * T_DIM + m0;
    const float* Bbase = q1 + (size_t)(b0 + lb) * TD + n0;
    float acc[8][8] = {};
    for (int kt = 0; kt < T_DIM; kt += BKK) {
        stage_a_colmajor_exp(As, Sbase + (size_t)kt * T_DIM, T_DIM, cmaxp, tid);
        stage_b_rowmajor(Bs, Bbase + (size_t)kt * D_DIM, D_DIM, tid);
        __syncthreads();
        gemm_inner(As, Bs, acc, tx, ty);
        __syncthreads();
    }
    float* Cp = out + (size_t)(b0 + lb) * TD + (size_t)m0 * D_DIM + n0;
#pragma unroll
    for (int i = 0; i < 8; ++i) {
        int r = ty * 8 + i;
        float inv = 1.0f / csump[r];
        float4 o0 = {acc[i][0] * inv, acc[i][1] * inv, acc[i][2] * inv, acc[i][3] * inv};
        float4 o1 = {acc[i][4] * inv, acc[i][5] * inv, acc[i][6] * inv, acc[i][7] * inv};
        *reinterpret_cast<float4*>(&Cp[(size_t)r * D_DIM + tx * 8]) = o0;
        *reinterpret_cast<float4*>(&Cp[(size_t)r * D_DIM + tx * 8 + 4]) = o1;
    }
}

// ===========================================================================
extern "C" void kernel_launch(void* const* d_in, const int* in_sizes, int n_in,
                              void* d_out, int out_size, void* d_ws, size_t ws_size,
                              hipStream_t stream) {
    const float* q1 = (const float*)d_in[0];
    const float* q2 = (const float*)d_in[1];
    const float* U  = (const float*)d_in[2];
    float* out = (float*)d_out;

    const size_t BT  = (size_t)B_DIM * T_DIM;       // 32768
    const size_t BTD = (size_t)B_DIM * TD;          // 33.55M
    const size_t DD  = (size_t)D_DIM * D_DIM;       // 1.05M

    // ---- fp16 MFMA path sizing ----
    const size_t fixedB = BT * 4 * 4                 // stats f32
                        + (4 * BTD + DD) * 2;        // q1h,q1ht,q2h,q2ht,Uht fp16
    const size_t perbB  = (size_t)TD * 2 + (size_t)TT * 4 + (size_t)TT * 4; // qUh + att + P2h/P1h
    int C = 64;
    while (C > 1 && fixedB + (size_t)C * perbB > ws_size) C >>= 1;

    if (fixedB + perbB <= ws_size) {
        float* rmax = (float*)d_ws;
        float* rsum = rmax + BT;
        float* cmax = rsum + BT;
        float* csum = cmax + BT;
        f16* q1h  = (f16*)(csum + BT);
        f16* q1ht = q1h  + BTD;
        f16* q2h  = q1ht + BTD;
        f16* q2ht = q2h  + BTD;
        f16* Uht  = q2ht + BTD;
        f16* qUh  = Uht  + DD;
        float* att = (float*)(qUh + (size_t)C * TD);
        f16* P2h  = (f16*)(att + (size_t)C * TT);
        f16* P1h  = P2h + (size_t)C * TT;

        k_cast_both<<<dim3(16, 8, 64), 256, 0, stream>>>(q1, q1h, q1ht);
        k_cast_both<<<dim3(16, 8, 64), 256, 0, stream>>>(q2, q2h, q2ht);
        k_castU<<<dim3(16, 16), 256, 0, stream>>>(U, Uht);

        for (int b0 = 0; b0 < B_DIM; b0 += C) {
            // qUh = q1h @ U   (M = C*512, N = K = 1024)
            k_mfma<0><<<dim3(8, C * 4, 1), 256, 0, stream>>>(
                q1h + (size_t)b0 * TD, D_DIM, Uht, D_DIM, D_DIM,
                qUh, D_DIM, nullptr, 0, 0, 0, 0);
            // att = relu(qUh @ q2^T)  per batch 512x512, K=1024
            k_mfma<1><<<dim3(4, 4, C), 256, 0, stream>>>(
                qUh, D_DIM, q2h + (size_t)b0 * TD, D_DIM, D_DIM,
                att, T_DIM, nullptr, (long)TD, (long)TD, (long)TT, 0);
            k_rowstats<<<dim3(C * T_DIM / 4), 256, 0, stream>>>(att, rmax, rsum, b0);
            k_colstats<<<dim3(T_DIM / 256, C), 256, 0, stream>>>(att, cmax, csum, b0);
            k_pconv<<<dim3(8, 8, C), 256, 0, stream>>>(att, rmax, cmax, P2h, P1h, b0);
            // q2_align (output 1): P2h @ q2, per batch 512x1024, K=512
            k_mfma<2><<<dim3(8, 4, C), 256, 0, stream>>>(
                P2h, T_DIM, q2ht + (size_t)b0 * TD, T_DIM, T_DIM,
                out + BTD + (size_t)b0 * TD, D_DIM, rsum + (size_t)b0 * T_DIM,
                (long)TT, (long)TD, (long)TD, T_DIM);
            // q1_align (output 0): P1h @ q1, per batch 512x1024, K=512
            k_mfma<3><<<dim3(8, 4, C), 256, 0, stream>>>(
                P1h, T_DIM, q1ht + (size_t)b0 * TD, T_DIM, T_DIM,
                out + (size_t)b0 * TD, D_DIM, csum + (size_t)b0 * T_DIM,
                (long)TT, (long)TD, (long)TD, T_DIM);
        }
        return;
    }

    // ---- fp32 fallback (round-1 proven) ----
    const size_t statsElems = 4ull * B_DIM * T_DIM;
    float* rmax = (float*)d_ws;
    float* rsum = rmax + BT;
    float* cmax = rsum + BT;
    float* csum = cmax + BT;
    float* scratch = csum + BT;
    size_t availFloats = (ws_size > statsElems * 4) ? (ws_size - statsElems * 4) / 4 : 0;
    int C2 = 64;
    while (C2 > 1 && (size_t)C2 * (TD + TT) > availFloats) C2 >>= 1;
    if ((size_t)C2 * (TD + TT) > availFloats) return;
    float* qU  = scratch;
    float* att = qU + (size_t)C2 * TD;
    for (int b0 = 0; b0 < B_DIM; b0 += C2) {
        k_gemm_qU<<<dim3(D_DIM / BN, C2 * (T_DIM / BM)), 256, 0, stream>>>(q1, U, qU, b0);
        k_att<<<dim3(T_DIM / BN, T_DIM / BM, C2), 256, 0, stream>>>(qU, q2, att, b0);
        k_rowstats<<<dim3(C2 * T_DIM / 4), 256, 0, stream>>>(att, rmax, rsum, b0);
        k_colstats<<<dim3(T_DIM / 256, C2), 256, 0, stream>>>(att, cmax, csum, b0);
        k_q2align<<<dim3(D_DIM / BN, T_DIM / BM, C2), 256, 0, stream>>>(att, q2, rmax, rsum, out, b0);
        k_q1align<<<dim3(D_DIM / BN, T_DIM / BM, C2), 256, 0, stream>>>(att, q1, cmax, csum, out, b0);
    }
}

// Round 3
// 483.660 us; speedup vs baseline: 4.2543x; 1.0879x over previous
//
#include <hip/hip_runtime.h>
#include <hip/hip_bf16.h>
#include <math.h>

#define B_DIM 64
#define T_DIM 512
#define D_DIM 1024
#define TT (T_DIM * T_DIM)   // 262144
#define TD (T_DIM * D_DIM)   // 524288

typedef _Float16 f16;
typedef f16 f16x4 __attribute__((ext_vector_type(4)));
typedef f16 f16x8 __attribute__((ext_vector_type(8)));
typedef float f32x4 __attribute__((ext_vector_type(4)));

// ===========================================================================
// FP16 MFMA path — 256x256 tile, BK=32, 8 waves, double-buffered LDS
// ===========================================================================

__device__ __forceinline__ void gld_lds16(const void* g, void* l) {
    __builtin_amdgcn_global_load_lds(
        (const __attribute__((address_space(1))) void*)g,
        (__attribute__((address_space(3))) void*)l, 16, 0, 0);
}

// C[M][N] = A[M][K] @ Bt[N][K]^T.  Tile 256x256, BK=32.
// 512 threads = 8 waves as 2(M)x4(N); per wave 128x64 = 8x4 frags of 16x16x32.
// LDS: per buf, A/B tile = 256 rows x 4 slots x 8 f16 (16KB); chunk ch=(row*4+j)
// at elem ch*8; LDS[row][j] holds global k-chunk (j ^ (row&3)) — swizzle applied
// on the global SOURCE address (linear LDS dest) and on the frag-read address.
// EPI: 0 = f16 out (qU)  1 = f32 out + relu (att)  2/3 = f32 out * 1/scale[row]
template <int EPI>
__global__ __launch_bounds__(512, 2) void k_mfma2(
        const f16* __restrict__ A, int lda,
        const f16* __restrict__ Bt, int ldb, int K,
        void* __restrict__ Cout, int ldc,
        const float* __restrict__ scale,
        long batchA, long batchB, long batchC, long batchS) {
    __shared__ f16 LA[2][8192];   // 2 x 16KB
    __shared__ f16 LB[2][8192];

    const int tid = threadIdx.x;
    const int lane = tid & 63, w = tid >> 6;

    // bijective XCD swizzle over the flattened grid (m204)
    const int gX = gridDim.x, gY = gridDim.y;
    int nwg = gX * gY * gridDim.z;
    int o = blockIdx.x + gX * (blockIdx.y + gY * blockIdx.z);
    int q8 = nwg >> 3, r8 = nwg & 7, xcd = o & 7, idx = o >> 3;
    int fl = (xcd < r8 ? xcd * (q8 + 1) : r8 * (q8 + 1) + (xcd - r8) * q8) + idx;
    const int bx = fl % gX;
    int tmp = fl / gX;
    const int by = tmp % gY;
    const int bz = tmp / gY;

    const f16* Ab = A + (long)bz * batchA + (long)(by * 256) * lda;
    const f16* Bb = Bt + (long)bz * batchB + (long)(bx * 256) * ldb;

    // staging decode: chunks ch0=tid, ch1=512+tid
    const int r0 = tid >> 2, s0 = (tid & 3) ^ (r0 & 3);
    const int r1 = (512 + tid) >> 2, s1 = ((512 + tid) & 3) ^ (r1 & 3);
    const long offA0 = (long)r0 * lda + s0 * 8;
    const long offA1 = (long)r1 * lda + s1 * 8;
    const long offB0 = (long)r0 * ldb + s0 * 8;
    const long offB1 = (long)r1 * ldb + s1 * 8;
    const int ldsOff0 = w * 512;          // elems; DMA adds lane*16B
    const int ldsOff1 = 4096 + w * 512;

    const int g = lane >> 4;
    const int rA0 = (w & 1) * 128 + (lane & 15);
    const int rB0 = (w >> 1) * 64 + (lane & 15);

    f32x4 acc[8][4] = {};

    // prologue: stage kt=0 into buf 0
    gld_lds16(Ab + offA0, &LA[0][ldsOff0]);
    gld_lds16(Ab + offA1, &LA[0][ldsOff1]);
    gld_lds16(Bb + offB0, &LB[0][ldsOff0]);
    gld_lds16(Bb + offB1, &LB[0][ldsOff1]);
    __syncthreads();

    const int NT = K >> 5;
    for (int t = 0; t < NT; ++t) {
        const int cur = t & 1;
        if (t + 1 < NT) {
            const long kt = (long)(t + 1) << 5;
            gld_lds16(Ab + offA0 + kt, &LA[cur ^ 1][ldsOff0]);
            gld_lds16(Ab + offA1 + kt, &LA[cur ^ 1][ldsOff1]);
            gld_lds16(Bb + offB0 + kt, &LB[cur ^ 1][ldsOff0]);
            gld_lds16(Bb + offB1 + kt, &LB[cur ^ 1][ldsOff1]);
        }
        f16x8 a[8], b[4];
#pragma unroll
        for (int m = 0; m < 8; ++m) {
            int r = rA0 + m * 16;
            a[m] = *(const f16x8*)(&LA[cur][r * 32 + ((g ^ (r & 3)) << 3)]);
        }
#pragma unroll
        for (int n = 0; n < 4; ++n) {
            int r = rB0 + n * 16;
            b[n] = *(const f16x8*)(&LB[cur][r * 32 + ((g ^ (r & 3)) << 3)]);
        }
#pragma unroll
        for (int m = 0; m < 8; ++m)
#pragma unroll
            for (int n = 0; n < 4; ++n)
                acc[m][n] = __builtin_amdgcn_mfma_f32_16x16x32_f16(a[m], b[n], acc[m][n], 0, 0, 0);
        __syncthreads();
    }

    const int row0 = by * 256 + (w & 1) * 128 + (lane >> 4) * 4;
    const int col0 = bx * 256 + (w >> 1) * 64 + (lane & 15);
    if constexpr (EPI == 0) {
        f16* C = (f16*)Cout;
#pragma unroll
        for (int m = 0; m < 8; ++m)
#pragma unroll
            for (int r = 0; r < 4; ++r) {
                long row = row0 + m * 16 + r;
#pragma unroll
                for (int n = 0; n < 4; ++n)
                    C[row * ldc + col0 + n * 16] = (f16)acc[m][n][r];
            }
    } else if constexpr (EPI == 1) {
        float* C = (float*)Cout + (long)bz * batchC;
#pragma unroll
        for (int m = 0; m < 8; ++m)
#pragma unroll
            for (int r = 0; r < 4; ++r) {
                long row = row0 + m * 16 + r;
#pragma unroll
                for (int n = 0; n < 4; ++n)
                    C[row * ldc + col0 + n * 16] = fmaxf(acc[m][n][r], 0.0f);
            }
    } else {
        float* C = (float*)Cout + (long)bz * batchC;
        const float* sz = scale + (long)bz * batchS;
#pragma unroll
        for (int m = 0; m < 8; ++m)
#pragma unroll
            for (int r = 0; r < 4; ++r) {
                long row = row0 + m * 16 + r;
                float inv = 1.0f / sz[row];
#pragma unroll
                for (int n = 0; n < 4; ++n)
                    C[row * ldc + col0 + n * 16] = acc[m][n][r] * inv;
            }
    }
}

// cast q [B][T][D] f32 -> qh fp16 [B][T][D] and qht fp16 [B][D][T]
__global__ __launch_bounds__(256) void k_cast_both(const float* __restrict__ src,
                                                   f16* __restrict__ dst,
                                                   f16* __restrict__ dstT) {
    __shared__ f16 tr[64][72];
    int b = blockIdx.z;
    int d0 = blockIdx.x * 64, t0 = blockIdx.y * 64;
    const float* S = src + ((size_t)b * T_DIM + t0) * D_DIM + d0;
    f16* Dr = dst + ((size_t)b * T_DIM + t0) * D_DIM + d0;
    int tid = threadIdx.x;
    int rr = tid >> 4, cc = (tid & 15) * 4;
#pragma unroll
    for (int i = 0; i < 4; ++i) {
        int r = rr + i * 16;
        float4 v = *(const float4*)(S + (size_t)r * D_DIM + cc);
        f16x4 h = {(f16)v.x, (f16)v.y, (f16)v.z, (f16)v.w};
        *(f16x4*)(Dr + (size_t)r * D_DIM + cc) = h;
        tr[cc + 0][r] = h[0];
        tr[cc + 1][r] = h[1];
        tr[cc + 2][r] = h[2];
        tr[cc + 3][r] = h[3];
    }
    __syncthreads();
    f16* Dt = dstT + ((size_t)b * D_DIM + d0) * T_DIM + t0;
    int r2 = tid >> 3, c8 = (tid & 7) * 8;
#pragma unroll
    for (int i = 0; i < 2; ++i) {
        int d = r2 + i * 32;
        f16x8 vv = *(const f16x8*)(&tr[d][c8]);
        *(f16x8*)(Dt + (size_t)d * T_DIM + c8) = vv;
    }
}

// U [K=1024][N=1024] f32 -> Uht fp16 [N][K]
__global__ __launch_bounds__(256) void k_castU(const float* __restrict__ U,
                                               f16* __restrict__ Uht) {
    __shared__ f16 tr[64][72];
    int n0 = blockIdx.x * 64, k0 = blockIdx.y * 64;
    int tid = threadIdx.x;
    int rr = tid >> 4, cc = (tid & 15) * 4;
#pragma unroll
    for (int i = 0; i < 4; ++i) {
        int r = rr + i * 16;
        float4 v = *(const float4*)(U + (size_t)(k0 + r) * D_DIM + n0 + cc);
        tr[cc + 0][r] = (f16)v.x;
        tr[cc + 1][r] = (f16)v.y;
        tr[cc + 2][r] = (f16)v.z;
        tr[cc + 3][r] = (f16)v.w;
    }
    __syncthreads();
    int r2 = tid >> 3, c8 = (tid & 7) * 8;
#pragma unroll
    for (int i = 0; i < 2; ++i) {
        int n = r2 + i * 32;
        f16x8 vv = *(const f16x8*)(&tr[n][c8]);
        *(f16x8*)(Uht + (size_t)(n0 + n) * D_DIM + k0 + c8) = vv;
    }
}

// att f32 (chunk-local) -> P2h[t][s] = exp(att - rmax[t]), P1h[s][t] = exp(att - cmax[s])
__global__ __launch_bounds__(256) void k_pconv(const float* __restrict__ att,
                                               const float* __restrict__ rmax,
                                               const float* __restrict__ cmax,
                                               f16* __restrict__ P2, f16* __restrict__ P1,
                                               int b0) {
    __shared__ f16 tr[64][72];
    int z = blockIdx.z;
    int t0 = blockIdx.y * 64, s0 = blockIdx.x * 64;
    const float* S = att + (size_t)z * TT + (size_t)t0 * T_DIM + s0;
    const float* rm = rmax + (size_t)(b0 + z) * T_DIM + t0;
    const float* cm = cmax + (size_t)(b0 + z) * T_DIM + s0;
    int tid = threadIdx.x;
    int rr = tid >> 4, cc = (tid & 15) * 4;
#pragma unroll
    for (int i = 0; i < 4; ++i) {
        int r = rr + i * 16;
        float4 v = *(const float4*)(S + (size_t)r * T_DIM + cc);
        float m = rm[r];
        f16x4 p2 = {(f16)__expf(v.x - m), (f16)__expf(v.y - m),
                    (f16)__expf(v.z - m), (f16)__expf(v.w - m)};
        *(f16x4*)(P2 + (size_t)z * TT + (size_t)(t0 + r) * T_DIM + s0 + cc) = p2;
        float4 c4 = *(const float4*)(cm + cc);
        tr[cc + 0][r] = (f16)__expf(v.x - c4.x);
        tr[cc + 1][r] = (f16)__expf(v.y - c4.y);
        tr[cc + 2][r] = (f16)__expf(v.z - c4.z);
        tr[cc + 3][r] = (f16)__expf(v.w - c4.w);
    }
    __syncthreads();
    int r2 = tid >> 3, c8 = (tid & 7) * 8;
#pragma unroll
    for (int i = 0; i < 2; ++i) {
        int s = r2 + i * 32;
        f16x8 vv = *(const f16x8*)(&tr[s][c8]);
        *(f16x8*)(P1 + (size_t)z * TT + (size_t)(s0 + s) * T_DIM + t0 + c8) = vv;
    }
}

// ---------------------------------------------------------------------------
// stats; att is chunk-local f32
// ---------------------------------------------------------------------------
__global__ __launch_bounds__(256) void k_rowstats(const float* __restrict__ att,
                                                  float* __restrict__ rmax,
                                                  float* __restrict__ rsum, int b0) {
    int wave = threadIdx.x >> 6, lane = threadIdx.x & 63;
    int lr = blockIdx.x * 4 + wave;
    const float4* row = reinterpret_cast<const float4*>(att + (size_t)lr * T_DIM);
    float4 v0 = row[lane];
    float4 v1 = row[lane + 64];
    float m = fmaxf(fmaxf(fmaxf(v0.x, v0.y), fmaxf(v0.z, v0.w)),
                    fmaxf(fmaxf(v1.x, v1.y), fmaxf(v1.z, v1.w)));
#pragma unroll
    for (int off = 32; off >= 1; off >>= 1) m = fmaxf(m, __shfl_xor(m, off));
    float s = __expf(v0.x - m) + __expf(v0.y - m) + __expf(v0.z - m) + __expf(v0.w - m)
            + __expf(v1.x - m) + __expf(v1.y - m) + __expf(v1.z - m) + __expf(v1.w - m);
#pragma unroll
    for (int off = 32; off >= 1; off >>= 1) s += __shfl_xor(s, off);
    if (lane == 0) {
        size_t gr = (size_t)b0 * T_DIM + lr;
        rmax[gr] = m;
        rsum[gr] = s;
    }
}

__global__ __launch_bounds__(256) void k_colstats(const float* __restrict__ att,
                                                  float* __restrict__ cmax,
                                                  float* __restrict__ csum, int b0) {
    int lb = blockIdx.y;
    int s = blockIdx.x * 256 + threadIdx.x;
    const float* base = att + (size_t)lb * TT + s;
    float m = -INFINITY, sum = 0.f;
    for (int t = 0; t < T_DIM; ++t) {
        float x = base[(size_t)t * T_DIM];
        float nm = fmaxf(m, x);
        sum = sum * __expf(m - nm) + __expf(x - nm);
        m = nm;
    }
    size_t g = (size_t)(b0 + lb) * T_DIM + s;
    cmax[g] = m;
    csum[g] = sum;
}

// ===========================================================================
// FP32 fallback path — used only if ws too small
// ===========================================================================
#define BM 128
#define BN 128
#define BKK 16
#define APITCH 132

__device__ __forceinline__ void stage_a_rowmajor(float* As, const float* __restrict__ A,
                                                 int lda, int tid) {
#pragma unroll
    for (int i = 0; i < 2; ++i) {
        int idx = tid + i * 256;
        int r = idx >> 2;
        int k4 = (idx & 3) << 2;
        float4 v = *reinterpret_cast<const float4*>(&A[(size_t)r * lda + k4]);
        As[(k4 + 0) * APITCH + r] = v.x;
        As[(k4 + 1) * APITCH + r] = v.y;
        As[(k4 + 2) * APITCH + r] = v.z;
        As[(k4 + 3) * APITCH + r] = v.w;
    }
}
__device__ __forceinline__ void stage_a_rowmajor_exp(float* As, const float* __restrict__ A,
                                                     int lda, const float* __restrict__ rowmax,
                                                     int tid) {
#pragma unroll
    for (int i = 0; i < 2; ++i) {
        int idx = tid + i * 256;
        int r = idx >> 2;
        int k4 = (idx & 3) << 2;
        float4 v = *reinterpret_cast<const float4*>(&A[(size_t)r * lda + k4]);
        float m = rowmax[r];
        As[(k4 + 0) * APITCH + r] = __expf(v.x - m);
        As[(k4 + 1) * APITCH + r] = __expf(v.y - m);
        As[(k4 + 2) * APITCH + r] = __expf(v.z - m);
        As[(k4 + 3) * APITCH + r] = __expf(v.w - m);
    }
}
__device__ __forceinline__ void stage_a_colmajor_exp(float* As, const float* __restrict__ S,
                                                     int lds, const float* __restrict__ colmax,
                                                     int tid) {
#pragma unroll
    for (int i = 0; i < 2; ++i) {
        int idx = tid + i * 256;
        int k = idx >> 5;
        int m4 = (idx & 31) << 2;
        float4 v = *reinterpret_cast<const float4*>(&S[(size_t)k * lds + m4]);
        float4 c = *reinterpret_cast<const float4*>(&colmax[m4]);
        float4 o;
        o.x = __expf(v.x - c.x); o.y = __expf(v.y - c.y);
        o.z = __expf(v.z - c.z); o.w = __expf(v.w - c.w);
        *reinterpret_cast<float4*>(&As[k * APITCH + m4]) = o;
    }
}
__device__ __forceinline__ void stage_b_rowmajor(float* Bs, const float* __restrict__ Bp,
                                                 int ldb, int tid) {
#pragma unroll
    for (int i = 0; i < 2; ++i) {
        int idx = tid + i * 256;
        int k = idx >> 5;
        int c4 = idx & 31;
        float4 v = *reinterpret_cast<const float4*>(&Bp[(size_t)k * ldb + (c4 << 2)]);
        *reinterpret_cast<float4*>(&Bs[k * BN + ((c4 & 1) << 6) + ((c4 >> 1) << 2)]) = v;
    }
}
__device__ __forceinline__ void stage_b_transpose(float* Bs, const float* __restrict__ Q,
                                                  int ldq, int tid) {
#pragma unroll
    for (int i = 0; i < 2; ++i) {
        int idx = tid + i * 256;
        int s = idx >> 2;
        int e4 = (idx & 3) << 2;
        float4 v = *reinterpret_cast<const float4*>(&Q[(size_t)s * ldq + e4]);
        int sw = ((s & 4) << 4) + ((s >> 3) << 2) + (s & 3);
        Bs[(e4 + 0) * BN + sw] = v.x;
        Bs[(e4 + 1) * BN + sw] = v.y;
        Bs[(e4 + 2) * BN + sw] = v.z;
        Bs[(e4 + 3) * BN + sw] = v.w;
    }
}
__device__ __forceinline__ void gemm_inner(const float* As, const float* Bs,
                                           float acc[8][8], int tx, int ty) {
#pragma unroll
    for (int k = 0; k < BKK; ++k) {
        float4 a0 = *reinterpret_cast<const float4*>(&As[k * APITCH + ty * 8]);
        float4 a1 = *reinterpret_cast<const float4*>(&As[k * APITCH + ty * 8 + 4]);
        float4 b0 = *reinterpret_cast<const float4*>(&Bs[k * BN + tx * 4]);
        float4 b1 = *reinterpret_cast<const float4*>(&Bs[k * BN + 64 + tx * 4]);
        float a[8] = {a0.x, a0.y, a0.z, a0.w, a1.x, a1.y, a1.z, a1.w};
        float b[8] = {b0.x, b0.y, b0.z, b0.w, b1.x, b1.y, b1.z, b1.w};
#pragma unroll
        for (int i = 0; i < 8; ++i)
#pragma unroll
            for (int j = 0; j < 8; ++j)
                acc[i][j] = fmaf(a[i], b[j], acc[i][j]);
    }
}
__global__ __launch_bounds__(256) void k_gemm_qU(const float* __restrict__ q1,
                                                 const float* __restrict__ U,
                                                 float* __restrict__ qU, int b0) {
    __shared__ float As[BKK * APITCH];
    __shared__ float Bs[BKK * BN];
    int tid = threadIdx.x, tx = tid & 15, ty = tid >> 4;
    int m0 = blockIdx.y * BM;
    int n0 = blockIdx.x * BN;
    const float* Abase = q1 + (size_t)b0 * TD + (size_t)m0 * D_DIM;
    const float* Bbase = U + n0;
    float acc[8][8] = {};
    for (int kt = 0; kt < D_DIM; kt += BKK) {
        stage_a_rowmajor(As, Abase + kt, D_DIM, tid);
        stage_b_rowmajor(Bs, Bbase + (size_t)kt * D_DIM, D_DIM, tid);
        __syncthreads();
        gemm_inner(As, Bs, acc, tx, ty);
        __syncthreads();
    }
    float* Cp = qU + (size_t)m0 * D_DIM + n0;
#pragma unroll
    for (int i = 0; i < 8; ++i) {
        int r = ty * 8 + i;
        float4 o0 = {acc[i][0], acc[i][1], acc[i][2], acc[i][3]};
        float4 o1 = {acc[i][4], acc[i][5], acc[i][6], acc[i][7]};
        *reinterpret_cast<float4*>(&Cp[(size_t)r * D_DIM + tx * 8]) = o0;
        *reinterpret_cast<float4*>(&Cp[(size_t)r * D_DIM + tx * 8 + 4]) = o1;
    }
}
__global__ __launch_bounds__(256) void k_att(const float* __restrict__ qU,
                                             const float* __restrict__ q2,
                                             float* __restrict__ att, int b0) {
    __shared__ float As[BKK * APITCH];
    __shared__ float Bs[BKK * BN];
    int tid = threadIdx.x, tx = tid & 15, ty = tid >> 4;
    int lb = blockIdx.z;
    int m0 = blockIdx.y * BM;
    int n0 = blockIdx.x * BN;
    const float* Abase = qU + (size_t)lb * TD + (size_t)m0 * D_DIM;
    const float* Qbase = q2 + (size_t)(b0 + lb) * TD + (size_t)n0 * D_DIM;
    float acc[8][8] = {};
    for (int kt = 0; kt < D_DIM; kt += BKK) {
        stage_a_rowmajor(As, Abase + kt, D_DIM, tid);
        stage_b_transpose(Bs, Qbase + kt, D_DIM, tid);
        __syncthreads();
        gemm_inner(As, Bs, acc, tx, ty);
        __syncthreads();
    }
    float* Cp = att + (size_t)lb * TT + (size_t)m0 * T_DIM + n0;
#pragma unroll
    for (int i = 0; i < 8; ++i) {
        int r = ty * 8 + i;
        float4 o0 = {fmaxf(acc[i][0], 0.f), fmaxf(acc[i][1], 0.f), fmaxf(acc[i][2], 0.f), fmaxf(acc[i][3], 0.f)};
        float4 o1 = {fmaxf(acc[i][4], 0.f), fmaxf(acc[i][5], 0.f), fmaxf(acc[i][6], 0.f), fmaxf(acc[i][7], 0.f)};
        *reinterpret_cast<float4*>(&Cp[(size_t)r * T_DIM + tx * 8]) = o0;
        *reinterpret_cast<float4*>(&Cp[(size_t)r * T_DIM + tx * 8 + 4]) = o1;
    }
}
__global__ __launch_bounds__(256) void k_q2align(const float* __restrict__ att,
                                                 const float* __restrict__ q2,
                                                 const float* __restrict__ rmax,
                                                 const float* __restrict__ rsum,
                                                 float* __restrict__ out, int b0) {
    __shared__ float As[BKK * APITCH];
    __shared__ float Bs[BKK * BN];
    int tid = threadIdx.x, tx = tid & 15, ty = tid >> 4;
    int lb = blockIdx.z;
    int m0 = blockIdx.y * BM;
    int n0 = blockIdx.x * BN;
    const float* Abase = att + (size_t)lb * TT + (size_t)m0 * T_DIM;
    const float* rmaxp = rmax + (size_t)(b0 + lb) * T_DIM + m0;
    const float* rsump = rsum + (size_t)(b0 + lb) * T_DIM + m0;
    const float* Bbase = q2 + (size_t)(b0 + lb) * TD + n0;
    float acc[8][8] = {};
    for (int kt = 0; kt < T_DIM; kt += BKK) {
        stage_a_rowmajor_exp(As, Abase + kt, T_DIM, rmaxp, tid);
        stage_b_rowmajor(Bs, Bbase + (size_t)kt * D_DIM, D_DIM, tid);
        __syncthreads();
        gemm_inner(As, Bs, acc, tx, ty);
        __syncthreads();
    }
    float* Cp = out + (size_t)B_DIM * TD + (size_t)(b0 + lb) * TD + (size_t)m0 * D_DIM + n0;
#pragma unroll
    for (int i = 0; i < 8; ++i) {
        int r = ty * 8 + i;
        float inv = 1.0f / rsump[r];
        float4 o0 = {acc[i][0] * inv, acc[i][1] * inv, acc[i][2] * inv, acc[i][3] * inv};
        float4 o1 = {acc[i][4] * inv, acc[i][5] * inv, acc[i][6] * inv, acc[i][7] * inv};
        *reinterpret_cast<float4*>(&Cp[(size_t)r * D_DIM + tx * 8]) = o0;
        *reinterpret_cast<float4*>(&Cp[(size_t)r * D_DIM + tx * 8 + 4]) = o1;
    }
}
__global__ __launch_bounds__(256) void k_q1align(const float* __restrict__ att,
                                                 const float* __restrict__ q1,
                                                 const float* __restrict__ cmax,
                                                 const float* __restrict__ csum,
                                                 float* __restrict__ out, int b0) {
    __shared__ float As[BKK * APITCH];
    __shared__ float Bs[BKK * BN];
    int tid = threadIdx.x, tx = tid & 15, ty = tid >> 4;
    int lb = blockIdx.z;
    int m0 = blockIdx.y * BM;
    int n0 = blockIdx.x * BN;
    const float* Sbase = att + (size_t)lb * TT + m0;
    const float* cmaxp = cmax + (size_t)(b0 + lb) * T_DIM + m0;
    const float* csump = csum + (size_t)(b0 + lb) * T_DIM + m0;
    const float* Bbase = q1 + (size_t)(b0 + lb) * TD + n0;
    float acc[8][8] = {};
    for (int kt = 0; kt < T_DIM; kt += BKK) {
        stage_a_colmajor_exp(As, Sbase + (size_t)kt * T_DIM, T_DIM, cmaxp, tid);
        stage_b_rowmajor(Bs, Bbase + (size_t)kt * D_DIM, D_DIM, tid);
        __syncthreads();
        gemm_inner(As, Bs, acc, tx, ty);
        __syncthreads();
    }
    float* Cp = out + (size_t)(b0 + lb) * TD + (size_t)m0 * D_DIM + n0;
#pragma unroll
    for (int i = 0; i < 8; ++i) {
        int r = ty * 8 + i;
        float inv = 1.0f / csump[r];
        float4 o0 = {acc[i][0] * inv, acc[i][1] * inv, acc[i][2] * inv, acc[i][3] * inv};
        float4 o1 = {acc[i][4] * inv, acc[i][5] * inv, acc[i][6] * inv, acc[i][7] * inv};
        *reinterpret_cast<float4*>(&Cp[(size_t)r * D_DIM + tx * 8]) = o0;
        *reinterpret_cast<float4*>(&Cp[(size_t)r * D_DIM + tx * 8 + 4]) = o1;
    }
}

// ===========================================================================
extern "C" void kernel_launch(void* const* d_in, const int* in_sizes, int n_in,
                              void* d_out, int out_size, void* d_ws, size_t ws_size,
                              hipStream_t stream) {
    const float* q1 = (const float*)d_in[0];
    const float* q2 = (const float*)d_in[1];
    const float* U  = (const float*)d_in[2];
    float* out = (float*)d_out;

    const size_t BT  = (size_t)B_DIM * T_DIM;       // 32768
    const size_t BTD = (size_t)B_DIM * TD;          // 33.55M
    const size_t DD  = (size_t)D_DIM * D_DIM;       // 1.05M

    // ---- fp16 MFMA path sizing ----
    const size_t fixedB = BT * 4 * 4                 // stats f32
                        + (4 * BTD + DD) * 2;        // q1h,q1ht,q2h,q2ht,Uht fp16
    const size_t perbB  = (size_t)TD * 2 + (size_t)TT * 4 + (size_t)TT * 4; // qUh + att + P2h/P1h
    int C = 64;
    while (C > 1 && fixedB + (size_t)C * perbB > ws_size) C >>= 1;

    if (fixedB + perbB <= ws_size) {
        float* rmax = (float*)d_ws;
        float* rsum = rmax + BT;
        float* cmax = rsum + BT;
        float* csum = cmax + BT;
        f16* q1h  = (f16*)(csum + BT);
        f16* q1ht = q1h  + BTD;
        f16* q2h  = q1ht + BTD;
        f16* q2ht = q2h  + BTD;
        f16* Uht  = q2ht + BTD;
        f16* qUh  = Uht  + DD;
        float* att = (float*)(qUh + (size_t)C * TD);
        f16* P2h  = (f16*)(att + (size_t)C * TT);
        f16* P1h  = P2h + (size_t)C * TT;

        k_cast_both<<<dim3(16, 8, 64), 256, 0, stream>>>(q1, q1h, q1ht);
        k_cast_both<<<dim3(16, 8, 64), 256, 0, stream>>>(q2, q2h, q2ht);
        k_castU<<<dim3(16, 16), 256, 0, stream>>>(U, Uht);

        for (int b0 = 0; b0 < B_DIM; b0 += C) {
            // qUh = q1h @ U   (M = C*512, N = K = 1024)
            k_mfma2<0><<<dim3(4, C * 2, 1), 512, 0, stream>>>(
                q1h + (size_t)b0 * TD, D_DIM, Uht, D_DIM, D_DIM,
                qUh, D_DIM, nullptr, 0, 0, 0, 0);
            // att = relu(qUh @ q2^T)  per batch 512x512, K=1024
            k_mfma2<1><<<dim3(2, 2, C), 512, 0, stream>>>(
                qUh, D_DIM, q2h + (size_t)b0 * TD, D_DIM, D_DIM,
                att, T_DIM, nullptr, (long)TD, (long)TD, (long)TT, 0);
            k_rowstats<<<dim3(C * T_DIM / 4), 256, 0, stream>>>(att, rmax, rsum, b0);
            k_colstats<<<dim3(T_DIM / 256, C), 256, 0, stream>>>(att, cmax, csum, b0);
            k_pconv<<<dim3(8, 8, C), 256, 0, stream>>>(att, rmax, cmax, P2h, P1h, b0);
            // q2_align (output 1): P2h @ q2^T-major, per batch 512x1024, K=512
            k_mfma2<2><<<dim3(4, 2, C), 512, 0, stream>>>(
                P2h, T_DIM, q2ht + (size_t)b0 * TD, T_DIM, T_DIM,
                out + BTD + (size_t)b0 * TD, D_DIM, rsum + (size_t)b0 * T_DIM,
                (long)TT, (long)TD, (long)TD, T_DIM);
            // q1_align (output 0): P1h @ q1^T-major, per batch 512x1024, K=512
            k_mfma2<3><<<dim3(4, 2, C), 512, 0, stream>>>(
                P1h, T_DIM, q1ht + (size_t)b0 * TD, T_DIM, T_DIM,
                out + (size_t)b0 * TD, D_DIM, csum + (size_t)b0 * T_DIM,
                (long)TT, (long)TD, (long)TD, T_DIM);
        }
        return;
    }

    // ---- fp32 fallback ----
    const size_t statsElems = 4ull * B_DIM * T_DIM;
    float* rmax = (float*)d_ws;
    float* rsum = rmax + BT;
    float* cmax = rsum + BT;
    float* csum = cmax + BT;
    float* scratch = csum + BT;
    size_t availFloats = (ws_size > statsElems * 4) ? (ws_size - statsElems * 4) / 4 : 0;
    int C2 = 64;
    while (C2 > 1 && (size_t)C2 * (TD + TT) > availFloats) C2 >>= 1;
    if ((size_t)C2 * (TD + TT) > availFloats) return;
    float* qU  = scratch;
    float* att = qU + (size_t)C2 * TD;
    for (int b0 = 0; b0 < B_DIM; b0 += C2) {
        k_gemm_qU<<<dim3(D_DIM / BN, C2 * (T_DIM / BM)), 256, 0, stream>>>(q1, U, qU, b0);
        k_att<<<dim3(T_DIM / BN, T_DIM / BM, C2), 256, 0, stream>>>(qU, q2, att, b0);
        k_rowstats<<<dim3(C2 * T_DIM / 4), 256, 0, stream>>>(att, rmax, rsum, b0);
        k_colstats<<<dim3(T_DIM / 256, C2), 256, 0, stream>>>(att, cmax, csum, b0);
        k_q2align<<<dim3(D_DIM / BN, T_DIM / BM, C2), 256, 0, stream>>>(att, q2, rmax, rsum, out, b0);
        k_q1align<<<dim3(D_DIM / BN, T_DIM / BM, C2), 256, 0, stream>>>(att, q1, cmax, csum, out, b0);
    }
}

// Round 4
// 451.785 us; speedup vs baseline: 4.5545x; 1.0706x over previous
//
#include <hip/hip_runtime.h>
#include <hip/hip_bf16.h>
#include <math.h>

#define B_DIM 64
#define T_DIM 512
#define D_DIM 1024
#define TT (T_DIM * T_DIM)   // 262144
#define TD (T_DIM * D_DIM)   // 524288

typedef _Float16 f16;
typedef f16 f16x4 __attribute__((ext_vector_type(4)));
typedef f16 f16x8 __attribute__((ext_vector_type(8)));
typedef float f32x4 __attribute__((ext_vector_type(4)));

// ===========================================================================
// FP16 MFMA path — 256x256 tile, BK=32, 8 waves, double-buffered LDS
// ===========================================================================

__device__ __forceinline__ void gld_lds16(const void* g, void* l) {
    __builtin_amdgcn_global_load_lds(
        (const __attribute__((address_space(1))) void*)g,
        (__attribute__((address_space(3))) void*)l, 16, 0, 0);
}

// C[M][N] = A[M][K] @ Bt[N][K]^T.  Tile 256x256, BK=32.
// 512 threads = 8 waves as 2(M)x4(N); per wave 128x64 = 8x4 frags of 16x16x32.
// LDS[row][j] holds global k-chunk (j ^ (row&3)) — swizzle applied on the
// global SOURCE address (linear LDS dest) and on the frag-read address.
// EPI: 0 = f16 out (qU)
//      1 = f32 out + relu (att) + fused row/col softmax partials -> rowP/colP
//      2 = f32 out * 1/scale[row]; dual-operand (bz>=zsplit selects set 2)
template <int EPI>
__global__ __launch_bounds__(512, 2) void k_mfma2(
        const f16* __restrict__ A, int lda,
        const f16* __restrict__ Bt, int ldb, int K,
        void* __restrict__ Cout, int ldc,
        const float* __restrict__ scale,
        long batchA, long batchB, long batchC, long batchS,
        float2* __restrict__ rowP, float2* __restrict__ colP, long pstr,
        const f16* __restrict__ A2, const f16* __restrict__ Bt2,
        void* __restrict__ Cout2, const float* __restrict__ scale2, int zsplit) {
    __shared__ f16 LA[2][8192];   // 2 x 16KB
    __shared__ f16 LB[2][8192];

    const int tid = threadIdx.x;
    const int lane = tid & 63, w = tid >> 6;

    // bijective XCD swizzle over the flattened grid (m204)
    const int gX = gridDim.x, gY = gridDim.y;
    int nwg = gX * gY * gridDim.z;
    int o = blockIdx.x + gX * (blockIdx.y + gY * blockIdx.z);
    int q8 = nwg >> 3, r8 = nwg & 7, xcd = o & 7, idx = o >> 3;
    int fl = (xcd < r8 ? xcd * (q8 + 1) : r8 * (q8 + 1) + (xcd - r8) * q8) + idx;
    const int bx = fl % gX;
    int tmp = fl / gX;
    const int by = tmp % gY;
    const int bz = tmp / gY;

    // dual-operand select (merged align GEMMs)
    const f16* Au = A; const f16* Bu = Bt;
    void* Cu = Cout; const float* su = scale;
    int zb = bz;
    if constexpr (EPI == 2) {
        if (bz >= zsplit) {
            zb = bz - zsplit;
            Au = A2; Bu = Bt2; Cu = Cout2; su = scale2;
        }
    }

    const f16* Ab = Au + (long)zb * batchA + (long)(by * 256) * lda;
    const f16* Bb = Bu + (long)zb * batchB + (long)(bx * 256) * ldb;

    // staging decode: chunks ch0=tid, ch1=512+tid
    const int r0 = tid >> 2, s0 = (tid & 3) ^ (r0 & 3);
    const int r1 = (512 + tid) >> 2, s1 = ((512 + tid) & 3) ^ (r1 & 3);
    const long offA0 = (long)r0 * lda + s0 * 8;
    const long offA1 = (long)r1 * lda + s1 * 8;
    const long offB0 = (long)r0 * ldb + s0 * 8;
    const long offB1 = (long)r1 * ldb + s1 * 8;
    const int ldsOff0 = w * 512;          // elems; DMA adds lane*16B
    const int ldsOff1 = 4096 + w * 512;

    const int g = lane >> 4;
    const int rA0 = (w & 1) * 128 + (lane & 15);
    const int rB0 = (w >> 1) * 64 + (lane & 15);

    f32x4 acc[8][4] = {};

    gld_lds16(Ab + offA0, &LA[0][ldsOff0]);
    gld_lds16(Ab + offA1, &LA[0][ldsOff1]);
    gld_lds16(Bb + offB0, &LB[0][ldsOff0]);
    gld_lds16(Bb + offB1, &LB[0][ldsOff1]);
    __syncthreads();

    const int NT = K >> 5;
    for (int t = 0; t < NT; ++t) {
        const int cur = t & 1;
        if (t + 1 < NT) {
            const long kt = (long)(t + 1) << 5;
            gld_lds16(Ab + offA0 + kt, &LA[cur ^ 1][ldsOff0]);
            gld_lds16(Ab + offA1 + kt, &LA[cur ^ 1][ldsOff1]);
            gld_lds16(Bb + offB0 + kt, &LB[cur ^ 1][ldsOff0]);
            gld_lds16(Bb + offB1 + kt, &LB[cur ^ 1][ldsOff1]);
        }
        f16x8 a[8], b[4];
#pragma unroll
        for (int m = 0; m < 8; ++m) {
            int r = rA0 + m * 16;
            a[m] = *(const f16x8*)(&LA[cur][r * 32 + ((g ^ (r & 3)) << 3)]);
        }
#pragma unroll
        for (int n = 0; n < 4; ++n) {
            int r = rB0 + n * 16;
            b[n] = *(const f16x8*)(&LB[cur][r * 32 + ((g ^ (r & 3)) << 3)]);
        }
#pragma unroll
        for (int m = 0; m < 8; ++m)
#pragma unroll
            for (int n = 0; n < 4; ++n)
                acc[m][n] = __builtin_amdgcn_mfma_f32_16x16x32_f16(a[m], b[n], acc[m][n], 0, 0, 0);
        __syncthreads();
    }

    const int row0 = by * 256 + (w & 1) * 128 + (lane >> 4) * 4;
    const int col0 = bx * 256 + (w >> 1) * 64 + (lane & 15);

    if constexpr (EPI == 0) {
        f16* C = (f16*)Cu;
#pragma unroll
        for (int m = 0; m < 8; ++m)
#pragma unroll
            for (int r = 0; r < 4; ++r) {
                long row = row0 + m * 16 + r;
#pragma unroll
                for (int n = 0; n < 4; ++n)
                    C[row * ldc + col0 + n * 16] = (f16)acc[m][n][r];
            }
    } else if constexpr (EPI == 1) {
        // relu in-place, then store att
#pragma unroll
        for (int m = 0; m < 8; ++m)
#pragma unroll
            for (int n = 0; n < 4; ++n)
#pragma unroll
                for (int r = 0; r < 4; ++r)
                    acc[m][n][r] = fmaxf(acc[m][n][r], 0.0f);
        float* C = (float*)Cu + (long)zb * batchC;
#pragma unroll
        for (int m = 0; m < 8; ++m)
#pragma unroll
            for (int r = 0; r < 4; ++r) {
                long row = row0 + m * 16 + r;
#pragma unroll
                for (int n = 0; n < 4; ++n)
                    C[row * ldc + col0 + n * 16] = acc[m][n][r];
            }
        // ---- fused softmax partials ----
        // reuse LA as scratch: redR[2][128][4][2] (2048 f32) + redC[2][256][2] (1024 f32)
        float* redR = (float*)(&LA[0][0]);
        float* redC = redR + 2048;
        const int h = w & 1, cw = w >> 1;
        // row partials: per (m,r), reduce over n-frags + lane&15 group (64 cols)
#pragma unroll
        for (int m = 0; m < 8; ++m)
#pragma unroll
            for (int r = 0; r < 4; ++r) {
                float mx = fmaxf(fmaxf(acc[m][0][r], acc[m][1][r]),
                                 fmaxf(acc[m][2][r], acc[m][3][r]));
                mx = fmaxf(mx, __shfl_xor(mx, 1));
                mx = fmaxf(mx, __shfl_xor(mx, 2));
                mx = fmaxf(mx, __shfl_xor(mx, 4));
                mx = fmaxf(mx, __shfl_xor(mx, 8));
                float sm = __expf(acc[m][0][r] - mx) + __expf(acc[m][1][r] - mx)
                         + __expf(acc[m][2][r] - mx) + __expf(acc[m][3][r] - mx);
                sm += __shfl_xor(sm, 1);
                sm += __shfl_xor(sm, 2);
                sm += __shfl_xor(sm, 4);
                sm += __shfl_xor(sm, 8);
                if ((lane & 15) == 0) {
                    int lr = m * 16 + (lane >> 4) * 4 + r;
                    redR[((h * 128 + lr) * 4 + cw) * 2 + 0] = mx;
                    redR[((h * 128 + lr) * 4 + cw) * 2 + 1] = sm;
                }
            }
        // col partials: per n-frag, reduce over (m,r) + lane>>4 groups (128 rows of half h)
#pragma unroll
        for (int n = 0; n < 4; ++n) {
            float mx = acc[0][n][0];
#pragma unroll
            for (int m = 0; m < 8; ++m)
#pragma unroll
                for (int r = 0; r < 4; ++r) mx = fmaxf(mx, acc[m][n][r]);
            mx = fmaxf(mx, __shfl_xor(mx, 16));
            mx = fmaxf(mx, __shfl_xor(mx, 32));
            float sm = 0.f;
#pragma unroll
            for (int m = 0; m < 8; ++m)
#pragma unroll
                for (int r = 0; r < 4; ++r) sm += __expf(acc[m][n][r] - mx);
            sm += __shfl_xor(sm, 16);
            sm += __shfl_xor(sm, 32);
            if (lane < 16) {
                int c = cw * 64 + n * 16 + lane;
                redC[(h * 256 + c) * 2 + 0] = mx;
                redC[(h * 256 + c) * 2 + 1] = sm;
            }
        }
        __syncthreads();
        if (tid < 256) {
            // merge 4 col-wave partials for block-row tid
            float M = -1e30f, S = 0.f;
#pragma unroll
            for (int i = 0; i < 4; ++i) {
                float m_ = redR[(tid * 4 + i) * 2 + 0];
                float s_ = redR[(tid * 4 + i) * 2 + 1];
                float nm = fmaxf(M, m_);
                S = S * __expf(M - nm) + s_ * __expf(m_ - nm);
                M = nm;
            }
            rowP[(long)bx * pstr + (long)bz * 512 + by * 256 + tid] = make_float2(M, S);
        } else {
            int c = tid - 256;
            float m0_ = redC[c * 2 + 0], s0_ = redC[c * 2 + 1];
            float m1_ = redC[(256 + c) * 2 + 0], s1_ = redC[(256 + c) * 2 + 1];
            float M = fmaxf(m0_, m1_);
            float S = s0_ * __expf(m0_ - M) + s1_ * __expf(m1_ - M);
            colP[(long)by * pstr + (long)bz * 512 + bx * 256 + c] = make_float2(M, S);
        }
    } else {
        float* C = (float*)Cu + (long)zb * batchC;
        const float* sz = su + (long)zb * batchS;
#pragma unroll
        for (int m = 0; m < 8; ++m)
#pragma unroll
            for (int r = 0; r < 4; ++r) {
                long row = row0 + m * 16 + r;
                float inv = 1.0f / sz[row];
#pragma unroll
                for (int n = 0; n < 4; ++n)
                    C[row * ldc + col0 + n * 16] = acc[m][n][r] * inv;
            }
    }
}

// merge the 2 partials per row and per col -> final stats
__global__ __launch_bounds__(256) void k_comb(const float2* __restrict__ rowP,
                                              const float2* __restrict__ colP, long pstr,
                                              float* __restrict__ rmax, float* __restrict__ rsum,
                                              float* __restrict__ cmax, float* __restrict__ csum,
                                              int b0, int n) {
    int i = blockIdx.x * 256 + threadIdx.x;
    if (i >= n) return;
    float2 a = rowP[i], b = rowP[pstr + i];
    float M = fmaxf(a.x, b.x);
    float S = a.y * __expf(a.x - M) + b.y * __expf(b.x - M);
    rmax[(size_t)b0 * T_DIM + i] = M;
    rsum[(size_t)b0 * T_DIM + i] = S;
    a = colP[i]; b = colP[pstr + i];
    M = fmaxf(a.x, b.x);
    S = a.y * __expf(a.x - M) + b.y * __expf(b.x - M);
    cmax[(size_t)b0 * T_DIM + i] = M;
    csum[(size_t)b0 * T_DIM + i] = S;
}

// cast q [B][T][D] f32 -> qh fp16 [B][T][D] and qht fp16 [B][D][T]
__global__ __launch_bounds__(256) void k_cast_both(const float* __restrict__ src,
                                                   f16* __restrict__ dst,
                                                   f16* __restrict__ dstT) {
    __shared__ f16 tr[64][72];
    int b = blockIdx.z;
    int d0 = blockIdx.x * 64, t0 = blockIdx.y * 64;
    const float* S = src + ((size_t)b * T_DIM + t0) * D_DIM + d0;
    f16* Dr = dst + ((size_t)b * T_DIM + t0) * D_DIM + d0;
    int tid = threadIdx.x;
    int rr = tid >> 4, cc = (tid & 15) * 4;
#pragma unroll
    for (int i = 0; i < 4; ++i) {
        int r = rr + i * 16;
        float4 v = *(const float4*)(S + (size_t)r * D_DIM + cc);
        f16x4 h = {(f16)v.x, (f16)v.y, (f16)v.z, (f16)v.w};
        *(f16x4*)(Dr + (size_t)r * D_DIM + cc) = h;
        tr[cc + 0][r] = h[0];
        tr[cc + 1][r] = h[1];
        tr[cc + 2][r] = h[2];
        tr[cc + 3][r] = h[3];
    }
    __syncthreads();
    f16* Dt = dstT + ((size_t)b * D_DIM + d0) * T_DIM + t0;
    int r2 = tid >> 3, c8 = (tid & 7) * 8;
#pragma unroll
    for (int i = 0; i < 2; ++i) {
        int d = r2 + i * 32;
        f16x8 vv = *(const f16x8*)(&tr[d][c8]);
        *(f16x8*)(Dt + (size_t)d * T_DIM + c8) = vv;
    }
}

// U [K=1024][N=1024] f32 -> Uht fp16 [N][K]
__global__ __launch_bounds__(256) void k_castU(const float* __restrict__ U,
                                               f16* __restrict__ Uht) {
    __shared__ f16 tr[64][72];
    int n0 = blockIdx.x * 64, k0 = blockIdx.y * 64;
    int tid = threadIdx.x;
    int rr = tid >> 4, cc = (tid & 15) * 4;
#pragma unroll
    for (int i = 0; i < 4; ++i) {
        int r = rr + i * 16;
        float4 v = *(const float4*)(U + (size_t)(k0 + r) * D_DIM + n0 + cc);
        tr[cc + 0][r] = (f16)v.x;
        tr[cc + 1][r] = (f16)v.y;
        tr[cc + 2][r] = (f16)v.z;
        tr[cc + 3][r] = (f16)v.w;
    }
    __syncthreads();
    int r2 = tid >> 3, c8 = (tid & 7) * 8;
#pragma unroll
    for (int i = 0; i < 2; ++i) {
        int n = r2 + i * 32;
        f16x8 vv = *(const f16x8*)(&tr[n][c8]);
        *(f16x8*)(Uht + (size_t)(n0 + n) * D_DIM + k0 + c8) = vv;
    }
}

// att f32 (chunk-local) -> P2h[t][s] = exp(att - rmax[t]), P1h[s][t] = exp(att - cmax[s])
__global__ __launch_bounds__(256) void k_pconv(const float* __restrict__ att,
                                               const float* __restrict__ rmax,
                                               const float* __restrict__ cmax,
                                               f16* __restrict__ P2, f16* __restrict__ P1,
                                               int b0) {
    __shared__ f16 tr[64][72];
    int z = blockIdx.z;
    int t0 = blockIdx.y * 64, s0 = blockIdx.x * 64;
    const float* S = att + (size_t)z * TT + (size_t)t0 * T_DIM + s0;
    const float* rm = rmax + (size_t)(b0 + z) * T_DIM + t0;
    const float* cm = cmax + (size_t)(b0 + z) * T_DIM + s0;
    int tid = threadIdx.x;
    int rr = tid >> 4, cc = (tid & 15) * 4;
#pragma unroll
    for (int i = 0; i < 4; ++i) {
        int r = rr + i * 16;
        float4 v = *(const float4*)(S + (size_t)r * T_DIM + cc);
        float m = rm[r];
        f16x4 p2 = {(f16)__expf(v.x - m), (f16)__expf(v.y - m),
                    (f16)__expf(v.z - m), (f16)__expf(v.w - m)};
        *(f16x4*)(P2 + (size_t)z * TT + (size_t)(t0 + r) * T_DIM + s0 + cc) = p2;
        float4 c4 = *(const float4*)(cm + cc);
        tr[cc + 0][r] = (f16)__expf(v.x - c4.x);
        tr[cc + 1][r] = (f16)__expf(v.y - c4.y);
        tr[cc + 2][r] = (f16)__expf(v.z - c4.z);
        tr[cc + 3][r] = (f16)__expf(v.w - c4.w);
    }
    __syncthreads();
    int r2 = tid >> 3, c8 = (tid & 7) * 8;
#pragma unroll
    for (int i = 0; i < 2; ++i) {
        int s = r2 + i * 32;
        f16x8 vv = *(const f16x8*)(&tr[s][c8]);
        *(f16x8*)(P1 + (size_t)z * TT + (size_t)(s0 + s) * T_DIM + t0 + c8) = vv;
    }
}

// ---------------------------------------------------------------------------
// standalone stats (fp32 fallback path only)
// ---------------------------------------------------------------------------
__global__ __launch_bounds__(256) void k_rowstats(const float* __restrict__ att,
                                                  float* __restrict__ rmax,
                                                  float* __restrict__ rsum, int b0) {
    int wave = threadIdx.x >> 6, lane = threadIdx.x & 63;
    int lr = blockIdx.x * 4 + wave;
    const float4* row = reinterpret_cast<const float4*>(att + (size_t)lr * T_DIM);
    float4 v0 = row[lane];
    float4 v1 = row[lane + 64];
    float m = fmaxf(fmaxf(fmaxf(v0.x, v0.y), fmaxf(v0.z, v0.w)),
                    fmaxf(fmaxf(v1.x, v1.y), fmaxf(v1.z, v1.w)));
#pragma unroll
    for (int off = 32; off >= 1; off >>= 1) m = fmaxf(m, __shfl_xor(m, off));
    float s = __expf(v0.x - m) + __expf(v0.y - m) + __expf(v0.z - m) + __expf(v0.w - m)
            + __expf(v1.x - m) + __expf(v1.y - m) + __expf(v1.z - m) + __expf(v1.w - m);
#pragma unroll
    for (int off = 32; off >= 1; off >>= 1) s += __shfl_xor(s, off);
    if (lane == 0) {
        size_t gr = (size_t)b0 * T_DIM + lr;
        rmax[gr] = m;
        rsum[gr] = s;
    }
}

__global__ __launch_bounds__(256) void k_colstats(const float* __restrict__ att,
                                                  float* __restrict__ cmax,
                                                  float* __restrict__ csum, int b0) {
    int lb = blockIdx.y;
    int s = blockIdx.x * 256 + threadIdx.x;
    const float* base = att + (size_t)lb * TT + s;
    float m = -INFINITY, sum = 0.f;
    for (int t = 0; t < T_DIM; ++t) {
        float x = base[(size_t)t * T_DIM];
        float nm = fmaxf(m, x);
        sum = sum * __expf(m - nm) + __expf(x - nm);
        m = nm;
    }
    size_t g = (size_t)(b0 + lb) * T_DIM + s;
    cmax[g] = m;
    csum[g] = sum;
}

// ===========================================================================
// FP32 fallback path — used only if ws too small
// ===========================================================================
#define BM 128
#define BN 128
#define BKK 16
#define APITCH 132

__device__ __forceinline__ void stage_a_rowmajor(float* As, const float* __restrict__ A,
                                                 int lda, int tid) {
#pragma unroll
    for (int i = 0; i < 2; ++i) {
        int idx = tid + i * 256;
        int r = idx >> 2;
        int k4 = (idx & 3) << 2;
        float4 v = *reinterpret_cast<const float4*>(&A[(size_t)r * lda + k4]);
        As[(k4 + 0) * APITCH + r] = v.x;
        As[(k4 + 1) * APITCH + r] = v.y;
        As[(k4 + 2) * APITCH + r] = v.z;
        As[(k4 + 3) * APITCH + r] = v.w;
    }
}
__device__ __forceinline__ void stage_a_rowmajor_exp(float* As, const float* __restrict__ A,
                                                     int lda, const float* __restrict__ rowmax,
                                                     int tid) {
#pragma unroll
    for (int i = 0; i < 2; ++i) {
        int idx = tid + i * 256;
        int r = idx >> 2;
        int k4 = (idx & 3) << 2;
        float4 v = *reinterpret_cast<const float4*>(&A[(size_t)r * lda + k4]);
        float m = rowmax[r];
        As[(k4 + 0) * APITCH + r] = __expf(v.x - m);
        As[(k4 + 1) * APITCH + r] = __expf(v.y - m);
        As[(k4 + 2) * APITCH + r] = __expf(v.z - m);
        As[(k4 + 3) * APITCH + r] = __expf(v.w - m);
    }
}
__device__ __forceinline__ void stage_a_colmajor_exp(float* As, const float* __restrict__ S,
                                                     int lds, const float* __restrict__ colmax,
                                                     int tid) {
#pragma unroll
    for (int i = 0; i < 2; ++i) {
        int idx = tid + i * 256;
        int k = idx >> 5;
        int m4 = (idx & 31) << 2;
        float4 v = *reinterpret_cast<const float4*>(&S[(size_t)k * lds + m4]);
        float4 c = *reinterpret_cast<const float4*>(&colmax[m4]);
        float4 o;
        o.x = __expf(v.x - c.x); o.y = __expf(v.y - c.y);
        o.z = __expf(v.z - c.z); o.w = __expf(v.w - c.w);
        *reinterpret_cast<float4*>(&As[k * APITCH + m4]) = o;
    }
}
__device__ __forceinline__ void stage_b_rowmajor(float* Bs, const float* __restrict__ Bp,
                                                 int ldb, int tid) {
#pragma unroll
    for (int i = 0; i < 2; ++i) {
        int idx = tid + i * 256;
        int k = idx >> 5;
        int c4 = idx & 31;
        float4 v = *reinterpret_cast<const float4*>(&Bp[(size_t)k * ldb + (c4 << 2)]);
        *reinterpret_cast<float4*>(&Bs[k * BN + ((c4 & 1) << 6) + ((c4 >> 1) << 2)]) = v;
    }
}
__device__ __forceinline__ void stage_b_transpose(float* Bs, const float* __restrict__ Q,
                                                  int ldq, int tid) {
#pragma unroll
    for (int i = 0; i < 2; ++i) {
        int idx = tid + i * 256;
        int s = idx >> 2;
        int e4 = (idx & 3) << 2;
        float4 v = *reinterpret_cast<const float4*>(&Q[(size_t)s * ldq + e4]);
        int sw = ((s & 4) << 4) + ((s >> 3) << 2) + (s & 3);
        Bs[(e4 + 0) * BN + sw] = v.x;
        Bs[(e4 + 1) * BN + sw] = v.y;
        Bs[(e4 + 2) * BN + sw] = v.z;
        Bs[(e4 + 3) * BN + sw] = v.w;
    }
}
__device__ __forceinline__ void gemm_inner(const float* As, const float* Bs,
                                           float acc[8][8], int tx, int ty) {
#pragma unroll
    for (int k = 0; k < BKK; ++k) {
        float4 a0 = *reinterpret_cast<const float4*>(&As[k * APITCH + ty * 8]);
        float4 a1 = *reinterpret_cast<const float4*>(&As[k * APITCH + ty * 8 + 4]);
        float4 b0 = *reinterpret_cast<const float4*>(&Bs[k * BN + tx * 4]);
        float4 b1 = *reinterpret_cast<const float4*>(&Bs[k * BN + 64 + tx * 4]);
        float a[8] = {a0.x, a0.y, a0.z, a0.w, a1.x, a1.y, a1.z, a1.w};
        float b[8] = {b0.x, b0.y, b0.z, b0.w, b1.x, b1.y, b1.z, b1.w};
#pragma unroll
        for (int i = 0; i < 8; ++i)
#pragma unroll
            for (int j = 0; j < 8; ++j)
                acc[i][j] = fmaf(a[i], b[j], acc[i][j]);
    }
}
__global__ __launch_bounds__(256) void k_gemm_qU(const float* __restrict__ q1,
                                                 const float* __restrict__ U,
                                                 float* __restrict__ qU, int b0) {
    __shared__ float As[BKK * APITCH];
    __shared__ float Bs[BKK * BN];
    int tid = threadIdx.x, tx = tid & 15, ty = tid >> 4;
    int m0 = blockIdx.y * BM;
    int n0 = blockIdx.x * BN;
    const float* Abase = q1 + (size_t)b0 * TD + (size_t)m0 * D_DIM;
    const float* Bbase = U + n0;
    float acc[8][8] = {};
    for (int kt = 0; kt < D_DIM; kt += BKK) {
        stage_a_rowmajor(As, Abase + kt, D_DIM, tid);
        stage_b_rowmajor(Bs, Bbase + (size_t)kt * D_DIM, D_DIM, tid);
        __syncthreads();
        gemm_inner(As, Bs, acc, tx, ty);
        __syncthreads();
    }
    float* Cp = qU + (size_t)m0 * D_DIM + n0;
#pragma unroll
    for (int i = 0; i < 8; ++i) {
        int r = ty * 8 + i;
        float4 o0 = {acc[i][0], acc[i][1], acc[i][2], acc[i][3]};
        float4 o1 = {acc[i][4], acc[i][5], acc[i][6], acc[i][7]};
        *reinterpret_cast<float4*>(&Cp[(size_t)r * D_DIM + tx * 8]) = o0;
        *reinterpret_cast<float4*>(&Cp[(size_t)r * D_DIM + tx * 8 + 4]) = o1;
    }
}
__global__ __launch_bounds__(256) void k_att(const float* __restrict__ qU,
                                             const float* __restrict__ q2,
                                             float* __restrict__ att, int b0) {
    __shared__ float As[BKK * APITCH];
    __shared__ float Bs[BKK * BN];
    int tid = threadIdx.x, tx = tid & 15, ty = tid >> 4;
    int lb = blockIdx.z;
    int m0 = blockIdx.y * BM;
    int n0 = blockIdx.x * BN;
    const float* Abase = qU + (size_t)lb * TD + (size_t)m0 * D_DIM;
    const float* Qbase = q2 + (size_t)(b0 + lb) * TD + (size_t)n0 * D_DIM;
    float acc[8][8] = {};
    for (int kt = 0; kt < D_DIM; kt += BKK) {
        stage_a_rowmajor(As, Abase + kt, D_DIM, tid);
        stage_b_transpose(Bs, Qbase + kt, D_DIM, tid);
        __syncthreads();
        gemm_inner(As, Bs, acc, tx, ty);
        __syncthreads();
    }
    float* Cp = att + (size_t)lb * TT + (size_t)m0 * T_DIM + n0;
#pragma unroll
    for (int i = 0; i < 8; ++i) {
        int r = ty * 8 + i;
        float4 o0 = {fmaxf(acc[i][0], 0.f), fmaxf(acc[i][1], 0.f), fmaxf(acc[i][2], 0.f), fmaxf(acc[i][3], 0.f)};
        float4 o1 = {fmaxf(acc[i][4], 0.f), fmaxf(acc[i][5], 0.f), fmaxf(acc[i][6], 0.f), fmaxf(acc[i][7], 0.f)};
        *reinterpret_cast<float4*>(&Cp[(size_t)r * T_DIM + tx * 8]) = o0;
        *reinterpret_cast<float4*>(&Cp[(size_t)r * T_DIM + tx * 8 + 4]) = o1;
    }
}
__global__ __launch_bounds__(256) void k_q2align(const float* __restrict__ att,
                                                 const float* __restrict__ q2,
                                                 const float* __restrict__ rmax,
                                                 const float* __restrict__ rsum,
                                                 float* __restrict__ out, int b0) {
    __shared__ float As[BKK * APITCH];
    __shared__ float Bs[BKK * BN];
    int tid = threadIdx.x, tx = tid & 15, ty = tid >> 4;
    int lb = blockIdx.z;
    int m0 = blockIdx.y * BM;
    int n0 = blockIdx.x * BN;
    const float* Abase = att + (size_t)lb * TT + (size_t)m0 * T_DIM;
    const float* rmaxp = rmax + (size_t)(b0 + lb) * T_DIM + m0;
    const float* rsump = rsum + (size_t)(b0 + lb) * T_DIM + m0;
    const float* Bbase = q2 + (size_t)(b0 + lb) * TD + n0;
    float acc[8][8] = {};
    for (int kt = 0; kt < T_DIM; kt += BKK) {
        stage_a_rowmajor_exp(As, Abase + kt, T_DIM, rmaxp, tid);
        stage_b_rowmajor(Bs, Bbase + (size_t)kt * D_DIM, D_DIM, tid);
        __syncthreads();
        gemm_inner(As, Bs, acc, tx, ty);
        __syncthreads();
    }
    float* Cp = out + (size_t)B_DIM * TD + (size_t)(b0 + lb) * TD + (size_t)m0 * D_DIM + n0;
#pragma unroll
    for (int i = 0; i < 8; ++i) {
        int r = ty * 8 + i;
        float inv = 1.0f / rsump[r];
        float4 o0 = {acc[i][0] * inv, acc[i][1] * inv, acc[i][2] * inv, acc[i][3] * inv};
        float4 o1 = {acc[i][4] * inv, acc[i][5] * inv, acc[i][6] * inv, acc[i][7] * inv};
        *reinterpret_cast<float4*>(&Cp[(size_t)r * D_DIM + tx * 8]) = o0;
        *reinterpret_cast<float4*>(&Cp[(size_t)r * D_DIM + tx * 8 + 4]) = o1;
    }
}
__global__ __launch_bounds__(256) void k_q1align(const float* __restrict__ att,
                                                 const float* __restrict__ q1,
                                                 const float* __restrict__ cmax,
                                                 const float* __restrict__ csum,
                                                 float* __restrict__ out, int b0) {
    __shared__ float As[BKK * APITCH];
    __shared__ float Bs[BKK * BN];
    int tid = threadIdx.x, tx = tid & 15, ty = tid >> 4;
    int lb = blockIdx.z;
    int m0 = blockIdx.y * BM;
    int n0 = blockIdx.x * BN;
    const float* Sbase = att + (size_t)lb * TT + m0;
    const float* cmaxp = cmax + (size_t)(b0 + lb) * T_DIM + m0;
    const float* csump = csum + (size_t)(b0 + lb) * T_DIM + m0;
    const float* Bbase = q1 + (size_t)(b0 + lb) * TD + n0;
    float acc[8][8] = {};
    for (int kt = 0; kt < T_DIM; kt += BKK) {
        stage_a_colmajor_exp(As, Sbase + (size_t)kt * T_DIM, T_DIM, cmaxp, tid);
        stage_b_rowmajor(Bs, Bbase + (size_t)kt * D_DIM, D_DIM, tid);
        __syncthreads();
        gemm_inner(As, Bs, acc, tx, ty);
        __syncthreads();
    }
    float* Cp = out + (size_t)(b0 + lb) * TD + (size_t)m0 * D_DIM + n0;
#pragma unroll
    for (int i = 0; i < 8; ++i) {
        int r = ty * 8 + i;
        float inv = 1.0f / csump[r];
        float4 o0 = {acc[i][0] * inv, acc[i][1] * inv, acc[i][2] * inv, acc[i][3] * inv};
        float4 o1 = {acc[i][4] * inv, acc[i][5] * inv, acc[i][6] * inv, acc[i][7] * inv};
        *reinterpret_cast<float4*>(&Cp[(size_t)r * D_DIM + tx * 8]) = o0;
        *reinterpret_cast<float4*>(&Cp[(size_t)r * D_DIM + tx * 8 + 4]) = o1;
    }
}

// ===========================================================================
extern "C" void kernel_launch(void* const* d_in, const int* in_sizes, int n_in,
                              void* d_out, int out_size, void* d_ws, size_t ws_size,
                              hipStream_t stream) {
    const float* q1 = (const float*)d_in[0];
    const float* q2 = (const float*)d_in[1];
    const float* U  = (const float*)d_in[2];
    float* out = (float*)d_out;

    const size_t BT  = (size_t)B_DIM * T_DIM;       // 32768
    const size_t BTD = (size_t)B_DIM * TD;          // 33.55M
    const size_t DD  = (size_t)D_DIM * D_DIM;       // 1.05M

    // ---- fp16 MFMA path sizing ----
    const size_t fixedB = BT * 4 * 4                 // stats f32
                        + (4 * BTD + DD) * 2;        // q1h,q1ht,q2h,q2ht,Uht fp16
    // per-chunk: qUh f16 + att f32 + P2h/P1h f16 + rowP/colP partials (2 each, float2)
    const size_t perbB  = (size_t)TD * 2 + (size_t)TT * 4 + (size_t)TT * 4
                        + 4ull * T_DIM * sizeof(float2);
    int C = 64;
    while (C > 1 && fixedB + (size_t)C * perbB > ws_size) C >>= 1;

    if (fixedB + perbB <= ws_size) {
        float* rmax = (float*)d_ws;
        float* rsum = rmax + BT;
        float* cmax = rsum + BT;
        float* csum = cmax + BT;
        f16* q1h  = (f16*)(csum + BT);
        f16* q1ht = q1h  + BTD;
        f16* q2h  = q1ht + BTD;
        f16* q2ht = q2h  + BTD;
        f16* Uht  = q2ht + BTD;
        f16* qUh  = Uht  + DD;
        float* att = (float*)(qUh + (size_t)C * TD);
        f16* P2h  = (f16*)(att + (size_t)C * TT);
        f16* P1h  = P2h + (size_t)C * TT;
        float2* rowP = (float2*)(P1h + (size_t)C * TT);     // [2][C*512]
        float2* colP = rowP + 2ull * C * T_DIM;             // [2][C*512]
        const long pstr = (long)C * T_DIM;

        k_cast_both<<<dim3(16, 8, 64), 256, 0, stream>>>(q1, q1h, q1ht);
        k_cast_both<<<dim3(16, 8, 64), 256, 0, stream>>>(q2, q2h, q2ht);
        k_castU<<<dim3(16, 16), 256, 0, stream>>>(U, Uht);

        for (int b0 = 0; b0 < B_DIM; b0 += C) {
            // qUh = q1h @ U   (M = C*512, N = K = 1024)
            k_mfma2<0><<<dim3(4, C * 2, 1), 512, 0, stream>>>(
                q1h + (size_t)b0 * TD, D_DIM, Uht, D_DIM, D_DIM,
                qUh, D_DIM, nullptr, 0, 0, 0, 0,
                nullptr, nullptr, 0, nullptr, nullptr, nullptr, nullptr, 0);
            // att = relu(qUh @ q2^T) + fused softmax partials
            k_mfma2<1><<<dim3(2, 2, C), 512, 0, stream>>>(
                qUh, D_DIM, q2h + (size_t)b0 * TD, D_DIM, D_DIM,
                att, T_DIM, nullptr, (long)TD, (long)TD, (long)TT, 0,
                rowP, colP, pstr, nullptr, nullptr, nullptr, nullptr, 0);
            // merge partials -> rmax/rsum/cmax/csum
            k_comb<<<dim3((C * T_DIM + 255) / 256), 256, 0, stream>>>(
                rowP, colP, pstr, rmax, rsum, cmax, csum, b0, C * T_DIM);
            k_pconv<<<dim3(8, 8, C), 256, 0, stream>>>(att, rmax, cmax, P2h, P1h, b0);
            // merged align GEMMs: z<C -> q2_align (out 1), z>=C -> q1_align (out 0)
            k_mfma2<2><<<dim3(4, 2, 2 * C), 512, 0, stream>>>(
                P2h, T_DIM, q2ht + (size_t)b0 * TD, T_DIM, T_DIM,
                out + BTD + (size_t)b0 * TD, D_DIM, rsum + (size_t)b0 * T_DIM,
                (long)TT, (long)TD, (long)TD, T_DIM,
                nullptr, nullptr, 0,
                P1h, q1ht + (size_t)b0 * TD,
                out + (size_t)b0 * TD, csum + (size_t)b0 * T_DIM, C);
        }
        return;
    }

    // ---- fp32 fallback ----
    const size_t statsElems = 4ull * B_DIM * T_DIM;
    float* rmax = (float*)d_ws;
    float* rsum = rmax + BT;
    float* cmax = rsum + BT;
    float* csum = cmax + BT;
    float* scratch = csum + BT;
    size_t availFloats = (ws_size > statsElems * 4) ? (ws_size - statsElems * 4) / 4 : 0;
    int C2 = 64;
    while (C2 > 1 && (size_t)C2 * (TD + TT) > availFloats) C2 >>= 1;
    if ((size_t)C2 * (TD + TT) > availFloats) return;
    float* qU  = scratch;
    float* att = qU + (size_t)C2 * TD;
    for (int b0 = 0; b0 < B_DIM; b0 += C2) {
        k_gemm_qU<<<dim3(D_DIM / BN, C2 * (T_DIM / BM)), 256, 0, stream>>>(q1, U, qU, b0);
        k_att<<<dim3(T_DIM / BN, T_DIM / BM, C2), 256, 0, stream>>>(qU, q2, att, b0);
        k_rowstats<<<dim3(C2 * T_DIM / 4), 256, 0, stream>>>(att, rmax, rsum, b0);
        k_colstats<<<dim3(T_DIM / 256, C2), 256, 0, stream>>>(att, cmax, csum, b0);
        k_q2align<<<dim3(D_DIM / BN, T_DIM / BM, C2), 256, 0, stream>>>(att, q2, rmax, rsum, out, b0);
        k_q1align<<<dim3(D_DIM / BN, T_DIM / BM, C2), 256, 0, stream>>>(att, q1, cmax, csum, out, b0);
    }
}